// Round 3
// baseline (890.762 us; speedup 1.0000x reference)
//
#include <hip/hip_runtime.h>
#include <hip/hip_bf16.h>

// ---------------------------------------------------------------------------
// TransportOperator: FISTA sparse coding through block-diag expm + transport.
// B=256, D=512, K=8, M=64, N=64.  20 FISTA iters, lr=0.01, lambda=0.05.
//
// R14 = champion (R6/R11) with ONE isolated change: krylov restructured to
// 1 wave per (b,k), 4 tiles per wg (grid 512):
//   - lane r owns row r of T (64 fp32 regs); matvec = 16 broadcast
//     ds_read_b128 + 64 per-lane FMA per level.  ZERO barriers (within-wave
//     LDS write->broadcast-read ordered by lgkmcnt; per-wave LDS slices).
//   - W-step per-lane in regs (kills the 100 ds_read_b32 of the champion).
//   - DS instr per (b,k): ~320 -> ~216; inter-wave coupling eliminated.
// gemm1 / gemm2 / fista are the exact champion versions (R13's gemm2
// 8-way split reverted: psiB re-reads doubled for no occupancy win).
// ---------------------------------------------------------------------------

typedef __attribute__((ext_vector_type(8))) short bf16x8;
typedef __attribute__((ext_vector_type(4))) float f32x4;
typedef unsigned short ushort_t;
typedef unsigned int uint_t;

__device__ __constant__ float INVF[20] = {
    1.0f, 1.0f, 0.5f, 1.6666666666666666e-1f, 4.1666666666666664e-2f,
    8.333333333333333e-3f, 1.3888888888888889e-3f, 1.984126984126984e-4f,
    2.48015873015873e-5f, 2.7557319223985893e-6f, 2.755731922398589e-7f,
    2.505210838544172e-8f, 2.08767569878681e-9f, 1.6059043836821613e-10f,
    1.1470745597729725e-11f, 7.647163731819816e-13f, 4.779477332387385e-14f,
    2.8114572543455206e-15f, 1.5619206968586225e-16f, 8.22063524662433e-18f};

__device__ __forceinline__ ushort_t f2b(float x) {
    uint_t u = __float_as_uint(x);
    uint_t r = u + 0x7FFFu + ((u >> 16) & 1u);   // RNE
    return (ushort_t)(r >> 16);
}
__device__ __forceinline__ float b2f(ushort_t h) {
    return __uint_as_float((uint_t)h << 16);
}

// --- one-time: psi -> psiB [k][m][uv], psiT [j][m]; zero c/y state ---------
__global__ __launch_bounds__(256) void prep_k(const float* __restrict__ psi,
                                              ushort_t* __restrict__ psiB,
                                              ushort_t* __restrict__ psiT,
                                              uint4* __restrict__ zero_base) {
    if (blockIdx.x < 48)   // zero 48*256*16 B = 196608 B (c,y fp32 + bf16)
        zero_base[blockIdx.x * 256 + threadIdx.x] = make_uint4(0, 0, 0, 0);
    int base = blockIdx.x * 2048 + threadIdx.x;
    for (int i = 0; i < 8; ++i) {
        int e = base + i * 256;                // e in [0, 2097152)
        float v = psi[e];
        ushort_t h = f2b(v);
        psiB[e] = h;
        int k = e >> 18;
        int r = e & 262143;
        int m = r >> 12;
        int uv = r & 4095;
        psiT[(size_t)k * 262144 + (size_t)uv * 64 + m] = h;
    }
}

// --- GEMM1: T[b][j] = sum_m y[b,m] * psiT[j,m].  D-rows <-> j. -------------
// grid 1024 = 512 j-windows x 2 b-halves (128 b).  18 KB LDS.
__global__ __launch_bounds__(256) void gemm1_k(const ushort_t* __restrict__ ybf,
                                               const ushort_t* __restrict__ psiT,
                                               ushort_t* __restrict__ Tbf) {
    __shared__ __align__(16) ushort_t Ls[128 * 72];   // [b 128][j 64] swizzled
    int wg = blockIdx.x;
    int j0 = (wg & 511) * 64;
    int bt = wg >> 9;                   // 0..1
    int tid = threadIdx.x;
    int wave = tid >> 6, lane = tid & 63;
    int rowi = lane & 15, q = lane >> 4;
    int b0w = bt * 128 + wave * 32;

    f32x4 acc[4][2];
    const f32x4 zero = {0.f, 0.f, 0.f, 0.f};
    for (int ta = 0; ta < 4; ++ta)
        for (int tb = 0; tb < 2; ++tb) acc[ta][tb] = zero;

    for (int ks = 0; ks < 2; ++ks) {
        bf16x8 a[4], bb[2];
        for (int ta = 0; ta < 4; ++ta)
            a[ta] = *(const bf16x8*)(psiT + (size_t)(j0 + ta * 16 + rowi) * 64 +
                                     ks * 32 + q * 8);
        for (int tb = 0; tb < 2; ++tb)
            bb[tb] = *(const bf16x8*)(ybf + (size_t)(b0w + tb * 16 + rowi) * 64 +
                                      ks * 32 + q * 8);
        for (int ta = 0; ta < 4; ++ta)
            for (int tb = 0; tb < 2; ++tb)
                acc[ta][tb] = __builtin_amdgcn_mfma_f32_16x16x32_bf16(
                    a[ta], bb[tb], acc[ta][tb], 0, 0, 0);
    }
    for (int ta = 0; ta < 4; ++ta)
        for (int tb = 0; tb < 2; ++tb) {
            int bl = wave * 32 + tb * 16 + rowi;      // local b in [0,128)
            int jl = ta * 16 + q * 4;
            uint_t lo = (uint_t)f2b(acc[ta][tb][0]) | ((uint_t)f2b(acc[ta][tb][1]) << 16);
            uint_t hi = (uint_t)f2b(acc[ta][tb][2]) | ((uint_t)f2b(acc[ta][tb][3]) << 16);
            int idx = bl * 72 + ((((jl >> 3) + 2 * bl) & 7) << 3) + (jl & 7);
            *(uint2*)&Ls[idx] = make_uint2(lo, hi);
        }
    __syncthreads();
    for (int pass = 0; pass < 4; ++pass) {
        int b = pass * 32 + (tid >> 3);               // local b
        int ch = tid & 7;
        uint4 v = *(const uint4*)&Ls[b * 72 + ch * 8];
        int x = (ch - 2 * b) & 7;
        *(uint4*)(Tbf + (size_t)(bt * 128 + b) * 32768 + j0 + x * 8) = v;
    }
}

// --- Krylov: 1 wave per (b,k), 4 per wg; T rows in regs; LDS broadcast. ----
// NO barriers: each wave uses only its own LDS slice; write->broadcast-read
// within a wave is ordered by compiler-inserted lgkmcnt waits.
// GRAD=1: writes O = sum_l W_l V_l^T over T.  GRAD=0: writes zhat to out.
template <int NT, int GRAD>
__global__ __launch_bounds__(256) void krylov_k(ushort_t* __restrict__ Tbf,
                                                const float* __restrict__ z0,
                                                const float* __restrict__ z1,
                                                float* __restrict__ out) {
    __shared__ __align__(16) float Vs[4][NT][64];   // per-wave V levels
    __shared__ __align__(16) float Bc[4][64];       // per-wave bwd broadcast
    int tid = threadIdx.x;
    int wv = tid >> 6, lane = tid & 63;
    int bid = blockIdx.x * 4 + wv;                  // (b,k) pair
    int b = bid >> 3, k = bid & 7;
    ushort_t* tbase = Tbf + (size_t)bid * 4096;

    // lane r owns row r of T: 64 bf16 = 8 x uint4
    float rowT[64];
    {
        const uint4* tp = (const uint4*)(tbase + (size_t)lane * 64);
#pragma unroll
        for (int cc = 0; cc < 8; ++cc) {
            uint4 v = tp[cc];
            uint_t w[4] = {v.x, v.y, v.z, v.w};
#pragma unroll
            for (int i = 0; i < 4; ++i) {
                rowT[cc * 8 + 2 * i]     = __uint_as_float(w[i] << 16);
                rowT[cc * 8 + 2 * i + 1] = __uint_as_float(w[i] & 0xFFFF0000u);
            }
        }
    }

    float vkeep[NT];
    vkeep[0] = z0[(size_t)b * 512 + k * 64 + lane];
    Vs[wv][0][lane] = vkeep[0];

#pragma unroll
    for (int l = 1; l < NT; ++l) {
        const f32x4* vp = (const f32x4*)&Vs[wv][l - 1][0];
        float a0 = 0.f, a1 = 0.f, a2 = 0.f, a3 = 0.f;
#pragma unroll
        for (int i = 0; i < 16; ++i) {
            f32x4 vv = vp[i];                        // broadcast read
            a0 = fmaf(rowT[4 * i + 0], vv[0], a0);
            a1 = fmaf(rowT[4 * i + 1], vv[1], a1);
            a2 = fmaf(rowT[4 * i + 2], vv[2], a2);
            a3 = fmaf(rowT[4 * i + 3], vv[3], a3);
        }
        float s = (a0 + a1) + (a2 + a3);
        vkeep[l] = s;
        Vs[wv][l][lane] = s;
    }

    float zh = 0.f;
#pragma unroll
    for (int l = 0; l < NT; ++l) zh = fmaf(INVF[l], vkeep[l], zh);

    if constexpr (!GRAD) {
        out[(size_t)b * 512 + k * 64 + lane] = zh;
        return;
    } else {
        // lane c owns column c of T (coalesced 128B per instr, L1/L2-hot)
        float colT[64];
#pragma unroll
        for (int i = 0; i < 64; ++i)
            colT[i] = b2f(tbase[(size_t)i * 64 + lane]);

        float ukeep[NT];
        ukeep[0] = zh - z1[(size_t)b * 512 + k * 64 + lane];
#pragma unroll
        for (int j = 1; j < NT; ++j) {
            Bc[wv][lane] = ukeep[j - 1];
            const f32x4* up = (const f32x4*)&Bc[wv][0];
            float a0 = 0.f, a1 = 0.f, a2 = 0.f, a3 = 0.f;
#pragma unroll
            for (int i = 0; i < 16; ++i) {
                f32x4 uu = up[i];                    // broadcast read
                a0 = fmaf(colT[4 * i + 0], uu[0], a0);
                a1 = fmaf(colT[4 * i + 1], uu[1], a1);
                a2 = fmaf(colT[4 * i + 2], uu[2], a2);
                a3 = fmaf(colT[4 * i + 3], uu[3], a3);
            }
            ukeep[j] = (a0 + a1) + (a2 + a3);
        }

        // W entirely per-lane (no LDS)
        float W[NT];
#pragma unroll
        for (int l = 0; l < NT; ++l) {
            float w = 0.f;
#pragma unroll
            for (int j = 0; j < NT; ++j) w = fmaf(INVF[j + l + 1], ukeep[j], w);
            W[l] = w;
        }

        // O[lane][c] = sum_l W[l](per-lane) * V_l[c](broadcast)
        float o[64];
#pragma unroll
        for (int c = 0; c < 64; ++c) o[c] = 0.f;
#pragma unroll
        for (int l = 0; l < NT; ++l) {
            const f32x4* vp = (const f32x4*)&Vs[wv][l][0];
            float wl = W[l];
#pragma unroll
            for (int i = 0; i < 16; ++i) {
                f32x4 vv = vp[i];                    // broadcast read
                o[4 * i + 0] = fmaf(wl, vv[0], o[4 * i + 0]);
                o[4 * i + 1] = fmaf(wl, vv[1], o[4 * i + 1]);
                o[4 * i + 2] = fmaf(wl, vv[2], o[4 * i + 2]);
                o[4 * i + 3] = fmaf(wl, vv[3], o[4 * i + 3]);
            }
        }

        uint4* op = (uint4*)(tbase + (size_t)lane * 64);
#pragma unroll
        for (int cc = 0; cc < 8; ++cc) {
            uint_t w0 = (uint_t)f2b(o[cc * 8 + 0]) | ((uint_t)f2b(o[cc * 8 + 1]) << 16);
            uint_t w1 = (uint_t)f2b(o[cc * 8 + 2]) | ((uint_t)f2b(o[cc * 8 + 3]) << 16);
            uint_t w2 = (uint_t)f2b(o[cc * 8 + 4]) | ((uint_t)f2b(o[cc * 8 + 5]) << 16);
            uint_t w3 = (uint_t)f2b(o[cc * 8 + 6]) | ((uint_t)f2b(o[cc * 8 + 7]) << 16);
            op[cc] = make_uint4(w0, w1, w2, w3);
        }
    }
}

// --- GEMM2: gpart[kc][b][m] = sum_{uv in chunk} O[b][.] psiB[m][.] ---------
// grid 256 = 4 bt x 64 kc; 4 waves split the 512-long K-chunk; LDS reduce.
__global__ __launch_bounds__(256) void gemm2_k(const ushort_t* __restrict__ Obf,
                                               const ushort_t* __restrict__ psiB,
                                               float* __restrict__ gpart) {
    __shared__ __align__(16) float Lg[64 * 68];    // [b 64][m 64] stride 68
    int bt = blockIdx.x & 3;
    int kc = blockIdx.x >> 2;          // 0..63
    int k = kc >> 3;
    int uv0 = (kc & 7) * 512;
    int tid = threadIdx.x, wave = tid >> 6, lane = tid & 63;
    int rowi = lane & 15, q = lane >> 4;

    f32x4 acc[4][4];
    const f32x4 zero = {0.f, 0.f, 0.f, 0.f};
    for (int ta = 0; ta < 4; ++ta)
        for (int tb = 0; tb < 4; ++tb) acc[ta][tb] = zero;

    for (int ks = 0; ks < 4; ++ks) {
        int off = uv0 + wave * 128 + ks * 32 + q * 8;
        bf16x8 a[4], bb[4];
        for (int ta = 0; ta < 4; ++ta)
            a[ta] = *(const bf16x8*)(psiB + (size_t)k * 262144 +
                                     (size_t)(ta * 16 + rowi) * 4096 + off);
        for (int tb = 0; tb < 4; ++tb)
            bb[tb] = *(const bf16x8*)(Obf +
                                      (size_t)(bt * 64 + tb * 16 + rowi) * 32768 +
                                      k * 4096 + off);
        for (int ta = 0; ta < 4; ++ta)
            for (int tb = 0; tb < 4; ++tb)
                acc[ta][tb] = __builtin_amdgcn_mfma_f32_16x16x32_bf16(
                    a[ta], bb[tb], acc[ta][tb], 0, 0, 0);
    }
    for (int w = 0; w < 4; ++w) {
        if (wave == w) {
            for (int ta = 0; ta < 4; ++ta)
                for (int tb = 0; tb < 4; ++tb) {
                    float* dst = &Lg[(tb * 16 + rowi) * 68 + ta * 16 + q * 4];
                    if (w == 0) *(f32x4*)dst = acc[ta][tb];
                    else {
                        f32x4 t = *(const f32x4*)dst;
                        t += acc[ta][tb];
                        *(f32x4*)dst = t;
                    }
                }
        }
        __syncthreads();
    }
    int b = tid >> 2, mq = tid & 3;
    float* gp = gpart + (size_t)kc * 16384 + (size_t)(bt * 64 + b) * 64 + mq * 16;
    const float* lp = &Lg[b * 68 + mq * 16];
    for (int i = 0; i < 4; ++i)
        *(f32x4*)(gp + 4 * i) = *(const f32x4*)(lp + 4 * i);
}

// --- FISTA: reduce 64 partials + prox step; maintain fp32 + bf16 state -----
__global__ __launch_bounds__(256) void fista_update(const float* __restrict__ gpart,
                                                    float* __restrict__ cb,
                                                    float* __restrict__ yb,
                                                    ushort_t* __restrict__ cbf,
                                                    ushort_t* __restrict__ ybf,
                                                    int iter) {
    int idx = blockIdx.x * 256 + threadIdx.x;
    float a0 = 0.f, a1 = 0.f, a2 = 0.f, a3 = 0.f;
#pragma unroll
    for (int p = 0; p < 64; p += 4) {
        a0 += gpart[(size_t)p * 16384 + idx];
        a1 += gpart[(size_t)(p + 1) * 16384 + idx];
        a2 += gpart[(size_t)(p + 2) * 16384 + idx];
        a3 += gpart[(size_t)(p + 3) * 16384 + idx];
    }
    float gv = (a0 + a1) + (a2 + a3);
    float t = 1.f;
    for (int s = 0; s < iter; ++s) t = 0.5f * (1.f + sqrtf(1.f + 4.f * t * t));
    float tn = 0.5f * (1.f + sqrtf(1.f + 4.f * t * t));
    float beta = (t - 1.f) / tn;
    float co = cb[idx], yo = yb[idx];
    float a = yo - 0.01f * gv;
    float thr = 0.01f * 0.05f;
    float cn = copysignf(fmaxf(fabsf(a) - thr, 0.f), a);
    float yn = cn + beta * (cn - co);
    cb[idx] = cn;
    yb[idx] = yn;
    cbf[idx] = f2b(cn);
    ybf[idx] = f2b(yn);
}

extern "C" void kernel_launch(void* const* d_in, const int* in_sizes, int n_in,
                              void* d_out, int out_size, void* d_ws, size_t ws_size,
                              hipStream_t stream) {
    const float* z0 = (const float*)d_in[0];
    const float* z1 = (const float*)d_in[1];
    const float* psi = (const float*)d_in[2];
    float* out = (float*)d_out;

    char* w = (char*)d_ws;
    ushort_t* TO    = (ushort_t*)(w);                 // 16,777,216  (T, then O)
    ushort_t* psiB  = (ushort_t*)(w + 16777216);      //  4,194,304
    ushort_t* psiT  = (ushort_t*)(w + 20971520);      //  4,194,304
    float*    gpart = (float*)(w + 25165824);         //  4,194,304  (64 partials)
    float*    cbuf  = (float*)(w + 29360128);         //     65,536
    float*    ybuf  = (float*)(w + 29425664);         //     65,536
    ushort_t* cbf   = (ushort_t*)(w + 29491200);      //     32,768
    ushort_t* ybf   = (ushort_t*)(w + 29523968);      //     32,768
    // total 29,556,736 B

    // prep converts psi AND zeroes c/y state (196608 B) -- no memset node
    prep_k<<<1024, 256, 0, stream>>>(psi, psiB, psiT, (uint4*)(w + 29360128));

    for (int it = 0; it < 20; ++it) {
        gemm1_k<<<1024, 256, 0, stream>>>(ybf, psiT, TO);
        krylov_k<5, 1><<<512, 256, 0, stream>>>(TO, z0, z1, nullptr);
        gemm2_k<<<256, 256, 0, stream>>>(TO, psiB, gpart);
        fista_update<<<64, 256, 0, stream>>>(gpart, cbuf, ybuf, cbf, ybf, it);
    }

    gemm1_k<<<1024, 256, 0, stream>>>(cbf, psiT, TO);
    krylov_k<8, 0><<<512, 256, 0, stream>>>(TO, z0, z1, out);
}

// Round 4
// 869.393 us; speedup vs baseline: 1.0246x; 1.0246x over previous
//
#include <hip/hip_runtime.h>
#include <hip/hip_bf16.h>

// ---------------------------------------------------------------------------
// TransportOperator: FISTA sparse coding through block-diag expm + transport.
// B=256, D=512, K=8, M=64, N=64.  20 FISTA iters, lr=0.01, lambda=0.05.
//
// R15 = champion (844us) with two ISOLATED micro-wins (no restructure):
//   gemm1 (1024 wgs): champion verbatim.
//   krylov<5>/<8> (2048 wgs): champion verbatim (R12/R14 restructures both
//     lost: readlane doubles VALU; 1-wave/tile dies on VGPR occupancy).
//   gemm2 (256 wgs): SAME tiling/traffic as champion; epilogue switched to
//     per-wave private LDS partials (69.6 KB, free at 1 wg/CU) + ONE barrier
//     + pairwise readback (champion serialized 4 waves through 4 barriers).
//     [R13 bundled this with an 8-way bt-split that doubled psiB traffic and
//      masked it -- split reverted, epilogue kept.]
//   fista (16 wgs): 4 elems/thread via f32x4 (was 64 wgs scalar, latency-
//     bound); per-element accumulation order bit-identical.
// ---------------------------------------------------------------------------

typedef __attribute__((ext_vector_type(8))) short bf16x8;
typedef __attribute__((ext_vector_type(4))) float f32x4;
typedef unsigned short ushort_t;
typedef unsigned int uint_t;

__device__ __constant__ float INVF[20] = {
    1.0f, 1.0f, 0.5f, 1.6666666666666666e-1f, 4.1666666666666664e-2f,
    8.333333333333333e-3f, 1.3888888888888889e-3f, 1.984126984126984e-4f,
    2.48015873015873e-5f, 2.7557319223985893e-6f, 2.755731922398589e-7f,
    2.505210838544172e-8f, 2.08767569878681e-9f, 1.6059043836821613e-10f,
    1.1470745597729725e-11f, 7.647163731819816e-13f, 4.779477332387385e-14f,
    2.8114572543455206e-15f, 1.5619206968586225e-16f, 8.22063524662433e-18f};

__device__ __forceinline__ ushort_t f2b(float x) {
    uint_t u = __float_as_uint(x);
    uint_t r = u + 0x7FFFu + ((u >> 16) & 1u);   // RNE
    return (ushort_t)(r >> 16);
}
__device__ __forceinline__ float b2f(ushort_t h) {
    return __uint_as_float((uint_t)h << 16);
}

// quad sum via DPP (VALU pipe, no LDS ops)
__device__ __forceinline__ float qsum4(float s) {
    int a = __builtin_amdgcn_update_dpp(0, __float_as_int(s), 0xB1, 0xF, 0xF, true);
    s += __int_as_float(a);                       // xor 1
    int b = __builtin_amdgcn_update_dpp(0, __float_as_int(s), 0x4E, 0xF, 0xF, true);
    s += __int_as_float(b);                       // xor 2
    return s;
}

// --- one-time: psi -> psiB [k][m][uv], psiT [j][m]; zero c/y state ---------
__global__ __launch_bounds__(256) void prep_k(const float* __restrict__ psi,
                                              ushort_t* __restrict__ psiB,
                                              ushort_t* __restrict__ psiT,
                                              uint4* __restrict__ zero_base) {
    if (blockIdx.x < 48)   // zero 48*256*16 B = 196608 B (c,y fp32 + bf16)
        zero_base[blockIdx.x * 256 + threadIdx.x] = make_uint4(0, 0, 0, 0);
    int base = blockIdx.x * 2048 + threadIdx.x;
    for (int i = 0; i < 8; ++i) {
        int e = base + i * 256;                // e in [0, 2097152)
        float v = psi[e];
        ushort_t h = f2b(v);
        psiB[e] = h;
        int k = e >> 18;
        int r = e & 262143;
        int m = r >> 12;
        int uv = r & 4095;
        psiT[(size_t)k * 262144 + (size_t)uv * 64 + m] = h;
    }
}

// --- GEMM1: T[b][j] = sum_m y[b,m] * psiT[j,m].  D-rows <-> j. -------------
// grid 1024 = 512 j-windows x 2 b-halves (128 b).  18 KB LDS.
__global__ __launch_bounds__(256) void gemm1_k(const ushort_t* __restrict__ ybf,
                                               const ushort_t* __restrict__ psiT,
                                               ushort_t* __restrict__ Tbf) {
    __shared__ __align__(16) ushort_t Ls[128 * 72];   // [b 128][j 64] swizzled
    int wg = blockIdx.x;
    int j0 = (wg & 511) * 64;
    int bt = wg >> 9;                   // 0..1
    int tid = threadIdx.x;
    int wave = tid >> 6, lane = tid & 63;
    int rowi = lane & 15, q = lane >> 4;
    int b0w = bt * 128 + wave * 32;

    f32x4 acc[4][2];
    const f32x4 zero = {0.f, 0.f, 0.f, 0.f};
    for (int ta = 0; ta < 4; ++ta)
        for (int tb = 0; tb < 2; ++tb) acc[ta][tb] = zero;

    for (int ks = 0; ks < 2; ++ks) {
        bf16x8 a[4], bb[2];
        for (int ta = 0; ta < 4; ++ta)
            a[ta] = *(const bf16x8*)(psiT + (size_t)(j0 + ta * 16 + rowi) * 64 +
                                     ks * 32 + q * 8);
        for (int tb = 0; tb < 2; ++tb)
            bb[tb] = *(const bf16x8*)(ybf + (size_t)(b0w + tb * 16 + rowi) * 64 +
                                      ks * 32 + q * 8);
        for (int ta = 0; ta < 4; ++ta)
            for (int tb = 0; tb < 2; ++tb)
                acc[ta][tb] = __builtin_amdgcn_mfma_f32_16x16x32_bf16(
                    a[ta], bb[tb], acc[ta][tb], 0, 0, 0);
    }
    for (int ta = 0; ta < 4; ++ta)
        for (int tb = 0; tb < 2; ++tb) {
            int bl = wave * 32 + tb * 16 + rowi;      // local b in [0,128)
            int jl = ta * 16 + q * 4;
            uint_t lo = (uint_t)f2b(acc[ta][tb][0]) | ((uint_t)f2b(acc[ta][tb][1]) << 16);
            uint_t hi = (uint_t)f2b(acc[ta][tb][2]) | ((uint_t)f2b(acc[ta][tb][3]) << 16);
            int idx = bl * 72 + ((((jl >> 3) + 2 * bl) & 7) << 3) + (jl & 7);
            *(uint2*)&Ls[idx] = make_uint2(lo, hi);
        }
    __syncthreads();
    for (int pass = 0; pass < 4; ++pass) {
        int b = pass * 32 + (tid >> 3);               // local b
        int ch = tid & 7;
        uint4 v = *(const uint4*)&Ls[b * 72 + ch * 8];
        int x = (ch - 2 * b) & 7;
        *(uint4*)(Tbf + (size_t)(bt * 128 + b) * 32768 + j0 + x * 8) = v;
    }
}

// --- Krylov: per (b,k); T in registers; grad mode writes O over T. ---------
template <int NT>
__global__ __launch_bounds__(256) void krylov_k(ushort_t* __restrict__ Tbf,
                                                const float* __restrict__ z0,
                                                const float* __restrict__ z1,
                                                float* __restrict__ out) {
    __shared__ float V[NT][64];
    __shared__ float U[NT][64];
    __shared__ float zz[64];
    int bid = blockIdx.x;
    int b = bid >> 3, k = bid & 7;
    int tid = threadIdx.x;
    int row = tid >> 2, p = tid & 3, c0 = p * 16;
    bool grad = (out == nullptr);

    const ushort_t* tbase = Tbf + (size_t)bid * 4096;
    float rowT[16];
    {
        uint4 ra = *(const uint4*)(tbase + row * 64 + c0);
        uint4 rb = *(const uint4*)(tbase + row * 64 + c0 + 8);
        uint_t wv[8] = {ra.x, ra.y, ra.z, ra.w, rb.x, rb.y, rb.z, rb.w};
        for (int i = 0; i < 8; ++i) {
            rowT[2 * i]     = __uint_as_float(wv[i] << 16);
            rowT[2 * i + 1] = __uint_as_float(wv[i] & 0xFFFF0000u);
        }
    }
    float colT[16];
    if (grad) {
#pragma unroll
        for (int i = 0; i < 16; ++i) colT[i] = b2f(tbase[(c0 + i) * 64 + row]);
    }
    if (tid < 64) {
        V[0][tid] = z0[(size_t)b * 512 + k * 64 + tid];
        zz[tid]   = z1[(size_t)b * 512 + k * 64 + tid];
    }
    __syncthreads();

    for (int l = 1; l < NT; ++l) {
        const f32x4* vp = (const f32x4*)&V[l - 1][c0];
        f32x4 v0 = vp[0], v1 = vp[1], v2 = vp[2], v3 = vp[3];
        float s0 = 0.f, s1 = 0.f, s2 = 0.f, s3 = 0.f;
#pragma unroll
        for (int i = 0; i < 4; ++i) {
            s0 = fmaf(rowT[i], v0[i], s0);
            s1 = fmaf(rowT[4 + i], v1[i], s1);
            s2 = fmaf(rowT[8 + i], v2[i], s2);
            s3 = fmaf(rowT[12 + i], v3[i], s3);
        }
        float s = qsum4((s0 + s1) + (s2 + s3));
        if (p == 0) V[l][row] = s;
        __syncthreads();
    }

    if (!grad) {
        if (tid < 64) {
            float zh = 0.f;
#pragma unroll
            for (int l = 0; l < NT; ++l) zh = fmaf(INVF[l], V[l][tid], zh);
            out[(size_t)b * 512 + k * 64 + tid] = zh;
        }
        return;
    }

    if (tid < 64) {
        float zh = 0.f;
#pragma unroll
        for (int l = 0; l < NT; ++l) zh = fmaf(INVF[l], V[l][tid], zh);
        U[0][tid] = zh - zz[tid];
    }
    __syncthreads();

    for (int j = 1; j < NT; ++j) {
        const f32x4* up = (const f32x4*)&U[j - 1][c0];
        f32x4 u0 = up[0], u1 = up[1], u2 = up[2], u3 = up[3];
        float s0 = 0.f, s1 = 0.f, s2 = 0.f, s3 = 0.f;
#pragma unroll
        for (int i = 0; i < 4; ++i) {
            s0 = fmaf(colT[i], u0[i], s0);
            s1 = fmaf(colT[4 + i], u1[i], s1);
            s2 = fmaf(colT[8 + i], u2[i], s2);
            s3 = fmaf(colT[12 + i], u3[i], s3);
        }
        float s = qsum4((s0 + s1) + (s2 + s3));
        if (p == 0) U[j][row] = s;
        __syncthreads();
    }

    float W[NT];
#pragma unroll
    for (int l = 0; l < NT; ++l) {
        float w = 0.f;
#pragma unroll
        for (int j = 0; j < NT; ++j) w = fmaf(INVF[j + l + 1], U[j][row], w);
        W[l] = w;
    }
    float o[16];
#pragma unroll
    for (int i = 0; i < 16; ++i) o[i] = 0.f;
#pragma unroll
    for (int l = 0; l < NT; ++l) {
        const f32x4* vp = (const f32x4*)&V[l][c0];
        f32x4 a0 = vp[0], a1 = vp[1], a2 = vp[2], a3 = vp[3];
        float w = W[l];
#pragma unroll
        for (int i = 0; i < 4; ++i) {
            o[i]      = fmaf(w, a0[i], o[i]);
            o[4 + i]  = fmaf(w, a1[i], o[4 + i]);
            o[8 + i]  = fmaf(w, a2[i], o[8 + i]);
            o[12 + i] = fmaf(w, a3[i], o[12 + i]);
        }
    }
    uint_t ow[8];
#pragma unroll
    for (int i = 0; i < 8; ++i)
        ow[i] = (uint_t)f2b(o[2 * i]) | ((uint_t)f2b(o[2 * i + 1]) << 16);
    uint4* op = (uint4*)(Tbf + (size_t)bid * 4096 + row * 64 + c0);
    op[0] = make_uint4(ow[0], ow[1], ow[2], ow[3]);
    op[1] = make_uint4(ow[4], ow[5], ow[6], ow[7]);
}

// --- GEMM2: gpart[kc][b][m] = sum_{uv in chunk} O[b][.] psiB[m][.] ---------
// grid 256 = 4 bt x 64 kc (champion tiling/traffic); 4 waves split the
// 512-long K-chunk.  Epilogue: per-wave private LDS partials (69.6 KB, free
// at 1 wg/CU) + ONE barrier + pairwise readback.
__global__ __launch_bounds__(256) void gemm2_k(const ushort_t* __restrict__ Obf,
                                               const ushort_t* __restrict__ psiB,
                                               float* __restrict__ gpart) {
    __shared__ __align__(16) float Lg[4][64 * 68];    // [w][b 64][m 64] str 68
    int bt = blockIdx.x & 3;
    int kc = blockIdx.x >> 2;          // 0..63
    int k = kc >> 3;
    int uv0 = (kc & 7) * 512;
    int tid = threadIdx.x, wave = tid >> 6, lane = tid & 63;
    int rowi = lane & 15, q = lane >> 4;

    f32x4 acc[4][4];
    const f32x4 zero = {0.f, 0.f, 0.f, 0.f};
    for (int ta = 0; ta < 4; ++ta)
        for (int tb = 0; tb < 4; ++tb) acc[ta][tb] = zero;

    for (int ks = 0; ks < 4; ++ks) {
        int off = uv0 + wave * 128 + ks * 32 + q * 8;
        bf16x8 a[4], bb[4];
        for (int ta = 0; ta < 4; ++ta)
            a[ta] = *(const bf16x8*)(psiB + (size_t)k * 262144 +
                                     (size_t)(ta * 16 + rowi) * 4096 + off);
        for (int tb = 0; tb < 4; ++tb)
            bb[tb] = *(const bf16x8*)(Obf +
                                      (size_t)(bt * 64 + tb * 16 + rowi) * 32768 +
                                      k * 4096 + off);
        for (int ta = 0; ta < 4; ++ta)
            for (int tb = 0; tb < 4; ++tb)
                acc[ta][tb] = __builtin_amdgcn_mfma_f32_16x16x32_bf16(
                    a[ta], bb[tb], acc[ta][tb], 0, 0, 0);
    }
    float* lw = &Lg[wave][0];
    for (int ta = 0; ta < 4; ++ta)
        for (int tb = 0; tb < 4; ++tb)
            *(f32x4*)&lw[(tb * 16 + rowi) * 68 + ta * 16 + q * 4] = acc[ta][tb];
    __syncthreads();

    int b = tid >> 2, mq = tid & 3;
    const float* l0 = &Lg[0][b * 68 + mq * 16];
    float* gp = gpart + (size_t)kc * 16384 + (size_t)(bt * 64 + b) * 64 + mq * 16;
#pragma unroll
    for (int i = 0; i < 4; ++i) {
        f32x4 s0 = *(const f32x4*)(l0 + 4 * i);
        f32x4 s1 = *(const f32x4*)(l0 + 4352 + 4 * i);
        f32x4 s2 = *(const f32x4*)(l0 + 8704 + 4 * i);
        f32x4 s3 = *(const f32x4*)(l0 + 13056 + 4 * i);
        f32x4 s = (s0 + s1) + (s2 + s3);
        *(f32x4*)(gp + 4 * i) = s;
    }
}

// --- FISTA: reduce 64 partials + prox step; maintain fp32 + bf16 state -----
// 16 wgs, 4 elems/thread via f32x4 (coalesced dwordx4); per-element
// accumulation order identical to scalar champion (4 accs over p).
__global__ __launch_bounds__(256) void fista_update(const float* __restrict__ gpart,
                                                    float* __restrict__ cb,
                                                    float* __restrict__ yb,
                                                    ushort_t* __restrict__ cbf,
                                                    ushort_t* __restrict__ ybf,
                                                    int iter) {
    int idx = (blockIdx.x * 256 + threadIdx.x) * 4;
    const f32x4 zero = {0.f, 0.f, 0.f, 0.f};
    f32x4 a0 = zero, a1 = zero, a2 = zero, a3 = zero;
#pragma unroll
    for (int p = 0; p < 64; p += 4) {
        a0 += *(const f32x4*)(gpart + (size_t)p * 16384 + idx);
        a1 += *(const f32x4*)(gpart + (size_t)(p + 1) * 16384 + idx);
        a2 += *(const f32x4*)(gpart + (size_t)(p + 2) * 16384 + idx);
        a3 += *(const f32x4*)(gpart + (size_t)(p + 3) * 16384 + idx);
    }
    f32x4 gv = (a0 + a1) + (a2 + a3);
    float t = 1.f;
    for (int s = 0; s < iter; ++s) t = 0.5f * (1.f + sqrtf(1.f + 4.f * t * t));
    float tn = 0.5f * (1.f + sqrtf(1.f + 4.f * t * t));
    float beta = (t - 1.f) / tn;
    f32x4 co = *(const f32x4*)(cb + idx);
    f32x4 yo = *(const f32x4*)(yb + idx);
    f32x4 cn, yn;
    const float thr = 0.01f * 0.05f;
#pragma unroll
    for (int e = 0; e < 4; ++e) {
        float a = yo[e] - 0.01f * gv[e];
        float c = copysignf(fmaxf(fabsf(a) - thr, 0.f), a);
        cn[e] = c;
        yn[e] = c + beta * (c - co[e]);
    }
    *(f32x4*)(cb + idx) = cn;
    *(f32x4*)(yb + idx) = yn;
    uint2 cp, yp;
    cp.x = (uint_t)f2b(cn[0]) | ((uint_t)f2b(cn[1]) << 16);
    cp.y = (uint_t)f2b(cn[2]) | ((uint_t)f2b(cn[3]) << 16);
    yp.x = (uint_t)f2b(yn[0]) | ((uint_t)f2b(yn[1]) << 16);
    yp.y = (uint_t)f2b(yn[2]) | ((uint_t)f2b(yn[3]) << 16);
    *(uint2*)(cbf + idx) = cp;
    *(uint2*)(ybf + idx) = yp;
}

extern "C" void kernel_launch(void* const* d_in, const int* in_sizes, int n_in,
                              void* d_out, int out_size, void* d_ws, size_t ws_size,
                              hipStream_t stream) {
    const float* z0 = (const float*)d_in[0];
    const float* z1 = (const float*)d_in[1];
    const float* psi = (const float*)d_in[2];
    float* out = (float*)d_out;

    char* w = (char*)d_ws;
    ushort_t* TO    = (ushort_t*)(w);                 // 16,777,216  (T, then O)
    ushort_t* psiB  = (ushort_t*)(w + 16777216);      //  4,194,304
    ushort_t* psiT  = (ushort_t*)(w + 20971520);      //  4,194,304
    float*    gpart = (float*)(w + 25165824);         //  4,194,304  (64 partials)
    float*    cbuf  = (float*)(w + 29360128);         //     65,536
    float*    ybuf  = (float*)(w + 29425664);         //     65,536
    ushort_t* cbf   = (ushort_t*)(w + 29491200);      //     32,768
    ushort_t* ybf   = (ushort_t*)(w + 29523968);      //     32,768
    // total 29,556,736 B

    // prep converts psi AND zeroes c/y state (196608 B) -- no memset node
    prep_k<<<1024, 256, 0, stream>>>(psi, psiB, psiT, (uint4*)(w + 29360128));

    for (int it = 0; it < 20; ++it) {
        gemm1_k<<<1024, 256, 0, stream>>>(ybf, psiT, TO);
        krylov_k<5><<<2048, 256, 0, stream>>>(TO, z0, z1, nullptr);
        gemm2_k<<<256, 256, 0, stream>>>(TO, psiB, gpart);
        fista_update<<<16, 256, 0, stream>>>(gpart, cbuf, ybuf, cbf, ybf, it);
    }

    gemm1_k<<<1024, 256, 0, stream>>>(cbf, psiT, TO);
    krylov_k<8><<<2048, 256, 0, stream>>>(TO, z0, z1, out);
}

// Round 5
// 831.493 us; speedup vs baseline: 1.0713x; 1.0456x over previous
//
#include <hip/hip_runtime.h>
#include <hip/hip_bf16.h>

// ---------------------------------------------------------------------------
// TransportOperator: FISTA sparse coding through block-diag expm + transport.
// B=256, D=512, K=8, M=64, N=64.  20 FISTA iters, lr=0.01, lambda=0.05.
//
// R16 = champion (844us) byte-for-byte (R12-R15 probes on krylov/gemm2/fista
// all measured negative-or-noise; those axes are closed) + ONE structural
// win: iteration 0 is degenerate (y=0 -> T=0 -> expm=I), so its
// gemm1+krylov<5> pair collapses to a rank-1 outer product
//     O[b,k] = (z0-z1) z0^T     (bit-identical to the champion's fmaf path:
// fma-with-zero is exact, single rounding per product, same f2b).
// Launch: prep; outer0+gemm2+fista(it0); 19x full 4-node; gemm1+krylov<8>.
// ---------------------------------------------------------------------------

typedef __attribute__((ext_vector_type(8))) short bf16x8;
typedef __attribute__((ext_vector_type(4))) float f32x4;
typedef unsigned short ushort_t;
typedef unsigned int uint_t;

__device__ __constant__ float INVF[20] = {
    1.0f, 1.0f, 0.5f, 1.6666666666666666e-1f, 4.1666666666666664e-2f,
    8.333333333333333e-3f, 1.3888888888888889e-3f, 1.984126984126984e-4f,
    2.48015873015873e-5f, 2.7557319223985893e-6f, 2.755731922398589e-7f,
    2.505210838544172e-8f, 2.08767569878681e-9f, 1.6059043836821613e-10f,
    1.1470745597729725e-11f, 7.647163731819816e-13f, 4.779477332387385e-14f,
    2.8114572543455206e-15f, 1.5619206968586225e-16f, 8.22063524662433e-18f};

__device__ __forceinline__ ushort_t f2b(float x) {
    uint_t u = __float_as_uint(x);
    uint_t r = u + 0x7FFFu + ((u >> 16) & 1u);   // RNE
    return (ushort_t)(r >> 16);
}
__device__ __forceinline__ float b2f(ushort_t h) {
    return __uint_as_float((uint_t)h << 16);
}

// quad sum via DPP (VALU pipe, no LDS ops)
__device__ __forceinline__ float qsum4(float s) {
    int a = __builtin_amdgcn_update_dpp(0, __float_as_int(s), 0xB1, 0xF, 0xF, true);
    s += __int_as_float(a);                       // xor 1
    int b = __builtin_amdgcn_update_dpp(0, __float_as_int(s), 0x4E, 0xF, 0xF, true);
    s += __int_as_float(b);                       // xor 2
    return s;
}

// --- one-time: psi -> psiB [k][m][uv], psiT [j][m]; zero c/y state ---------
__global__ __launch_bounds__(256) void prep_k(const float* __restrict__ psi,
                                              ushort_t* __restrict__ psiB,
                                              ushort_t* __restrict__ psiT,
                                              uint4* __restrict__ zero_base) {
    if (blockIdx.x < 48)   // zero 48*256*16 B = 196608 B (c,y fp32 + bf16)
        zero_base[blockIdx.x * 256 + threadIdx.x] = make_uint4(0, 0, 0, 0);
    int base = blockIdx.x * 2048 + threadIdx.x;
    for (int i = 0; i < 8; ++i) {
        int e = base + i * 256;                // e in [0, 2097152)
        float v = psi[e];
        ushort_t h = f2b(v);
        psiB[e] = h;
        int k = e >> 18;
        int r = e & 262143;
        int m = r >> 12;
        int uv = r & 4095;
        psiT[(size_t)k * 262144 + (size_t)uv * 64 + m] = h;
    }
}

// --- iter-0 shortcut: O[b,k] = (z0-z1) z0^T (T=0 => expm=I), bit-identical
// to champion gemm1+krylov<5,grad> at y=0.  grid 2048 = one wg per (b,k).
__global__ __launch_bounds__(256) void outer0_k(const float* __restrict__ z0,
                                                const float* __restrict__ z1,
                                                ushort_t* __restrict__ Tbf) {
    int bid = blockIdx.x;
    int b = bid >> 3, k = bid & 7;
    int tid = threadIdx.x;
    int row = tid >> 2, p = tid & 3, c0 = p * 16;
    const float* zb = z0 + (size_t)b * 512 + k * 64;
    float u = zb[row] - z1[(size_t)b * 512 + k * 64 + row];
    const f32x4* vp = (const f32x4*)(zb + c0);
    f32x4 v0 = vp[0], v1 = vp[1], v2 = vp[2], v3 = vp[3];
    float o[16];
#pragma unroll
    for (int i = 0; i < 4; ++i) {
        o[i]      = u * v0[i];
        o[4 + i]  = u * v1[i];
        o[8 + i]  = u * v2[i];
        o[12 + i] = u * v3[i];
    }
    uint_t ow[8];
#pragma unroll
    for (int i = 0; i < 8; ++i)
        ow[i] = (uint_t)f2b(o[2 * i]) | ((uint_t)f2b(o[2 * i + 1]) << 16);
    uint4* op = (uint4*)(Tbf + (size_t)bid * 4096 + row * 64 + c0);
    op[0] = make_uint4(ow[0], ow[1], ow[2], ow[3]);
    op[1] = make_uint4(ow[4], ow[5], ow[6], ow[7]);
}

// --- GEMM1: T[b][j] = sum_m y[b,m] * psiT[j,m].  D-rows <-> j. -------------
// grid 1024 = 512 j-windows x 2 b-halves (128 b).  18 KB LDS.
__global__ __launch_bounds__(256) void gemm1_k(const ushort_t* __restrict__ ybf,
                                               const ushort_t* __restrict__ psiT,
                                               ushort_t* __restrict__ Tbf) {
    __shared__ __align__(16) ushort_t Ls[128 * 72];   // [b 128][j 64] swizzled
    int wg = blockIdx.x;
    int j0 = (wg & 511) * 64;
    int bt = wg >> 9;                   // 0..1
    int tid = threadIdx.x;
    int wave = tid >> 6, lane = tid & 63;
    int rowi = lane & 15, q = lane >> 4;
    int b0w = bt * 128 + wave * 32;

    f32x4 acc[4][2];
    const f32x4 zero = {0.f, 0.f, 0.f, 0.f};
    for (int ta = 0; ta < 4; ++ta)
        for (int tb = 0; tb < 2; ++tb) acc[ta][tb] = zero;

    for (int ks = 0; ks < 2; ++ks) {
        bf16x8 a[4], bb[2];
        for (int ta = 0; ta < 4; ++ta)
            a[ta] = *(const bf16x8*)(psiT + (size_t)(j0 + ta * 16 + rowi) * 64 +
                                     ks * 32 + q * 8);
        for (int tb = 0; tb < 2; ++tb)
            bb[tb] = *(const bf16x8*)(ybf + (size_t)(b0w + tb * 16 + rowi) * 64 +
                                      ks * 32 + q * 8);
        for (int ta = 0; ta < 4; ++ta)
            for (int tb = 0; tb < 2; ++tb)
                acc[ta][tb] = __builtin_amdgcn_mfma_f32_16x16x32_bf16(
                    a[ta], bb[tb], acc[ta][tb], 0, 0, 0);
    }
    for (int ta = 0; ta < 4; ++ta)
        for (int tb = 0; tb < 2; ++tb) {
            int bl = wave * 32 + tb * 16 + rowi;      // local b in [0,128)
            int jl = ta * 16 + q * 4;
            uint_t lo = (uint_t)f2b(acc[ta][tb][0]) | ((uint_t)f2b(acc[ta][tb][1]) << 16);
            uint_t hi = (uint_t)f2b(acc[ta][tb][2]) | ((uint_t)f2b(acc[ta][tb][3]) << 16);
            int idx = bl * 72 + ((((jl >> 3) + 2 * bl) & 7) << 3) + (jl & 7);
            *(uint2*)&Ls[idx] = make_uint2(lo, hi);
        }
    __syncthreads();
    for (int pass = 0; pass < 4; ++pass) {
        int b = pass * 32 + (tid >> 3);               // local b
        int ch = tid & 7;
        uint4 v = *(const uint4*)&Ls[b * 72 + ch * 8];
        int x = (ch - 2 * b) & 7;
        *(uint4*)(Tbf + (size_t)(bt * 128 + b) * 32768 + j0 + x * 8) = v;
    }
}

// --- Krylov: per (b,k); T in registers; grad mode writes O over T. ---------
template <int NT>
__global__ __launch_bounds__(256) void krylov_k(ushort_t* __restrict__ Tbf,
                                                const float* __restrict__ z0,
                                                const float* __restrict__ z1,
                                                float* __restrict__ out) {
    __shared__ float V[NT][64];
    __shared__ float U[NT][64];
    __shared__ float zz[64];
    int bid = blockIdx.x;
    int b = bid >> 3, k = bid & 7;
    int tid = threadIdx.x;
    int row = tid >> 2, p = tid & 3, c0 = p * 16;
    bool grad = (out == nullptr);

    const ushort_t* tbase = Tbf + (size_t)bid * 4096;
    float rowT[16];
    {
        uint4 ra = *(const uint4*)(tbase + row * 64 + c0);
        uint4 rb = *(const uint4*)(tbase + row * 64 + c0 + 8);
        uint_t wv[8] = {ra.x, ra.y, ra.z, ra.w, rb.x, rb.y, rb.z, rb.w};
        for (int i = 0; i < 8; ++i) {
            rowT[2 * i]     = __uint_as_float(wv[i] << 16);
            rowT[2 * i + 1] = __uint_as_float(wv[i] & 0xFFFF0000u);
        }
    }
    float colT[16];
    if (grad) {
#pragma unroll
        for (int i = 0; i < 16; ++i) colT[i] = b2f(tbase[(c0 + i) * 64 + row]);
    }
    if (tid < 64) {
        V[0][tid] = z0[(size_t)b * 512 + k * 64 + tid];
        zz[tid]   = z1[(size_t)b * 512 + k * 64 + tid];
    }
    __syncthreads();

    for (int l = 1; l < NT; ++l) {
        const f32x4* vp = (const f32x4*)&V[l - 1][c0];
        f32x4 v0 = vp[0], v1 = vp[1], v2 = vp[2], v3 = vp[3];
        float s0 = 0.f, s1 = 0.f, s2 = 0.f, s3 = 0.f;
#pragma unroll
        for (int i = 0; i < 4; ++i) {
            s0 = fmaf(rowT[i], v0[i], s0);
            s1 = fmaf(rowT[4 + i], v1[i], s1);
            s2 = fmaf(rowT[8 + i], v2[i], s2);
            s3 = fmaf(rowT[12 + i], v3[i], s3);
        }
        float s = qsum4((s0 + s1) + (s2 + s3));
        if (p == 0) V[l][row] = s;
        __syncthreads();
    }

    if (!grad) {
        if (tid < 64) {
            float zh = 0.f;
#pragma unroll
            for (int l = 0; l < NT; ++l) zh = fmaf(INVF[l], V[l][tid], zh);
            out[(size_t)b * 512 + k * 64 + tid] = zh;
        }
        return;
    }

    if (tid < 64) {
        float zh = 0.f;
#pragma unroll
        for (int l = 0; l < NT; ++l) zh = fmaf(INVF[l], V[l][tid], zh);
        U[0][tid] = zh - zz[tid];
    }
    __syncthreads();

    for (int j = 1; j < NT; ++j) {
        const f32x4* up = (const f32x4*)&U[j - 1][c0];
        f32x4 u0 = up[0], u1 = up[1], u2 = up[2], u3 = up[3];
        float s0 = 0.f, s1 = 0.f, s2 = 0.f, s3 = 0.f;
#pragma unroll
        for (int i = 0; i < 4; ++i) {
            s0 = fmaf(colT[i], u0[i], s0);
            s1 = fmaf(colT[4 + i], u1[i], s1);
            s2 = fmaf(colT[8 + i], u2[i], s2);
            s3 = fmaf(colT[12 + i], u3[i], s3);
        }
        float s = qsum4((s0 + s1) + (s2 + s3));
        if (p == 0) U[j][row] = s;
        __syncthreads();
    }

    float W[NT];
#pragma unroll
    for (int l = 0; l < NT; ++l) {
        float w = 0.f;
#pragma unroll
        for (int j = 0; j < NT; ++j) w = fmaf(INVF[j + l + 1], U[j][row], w);
        W[l] = w;
    }
    float o[16];
#pragma unroll
    for (int i = 0; i < 16; ++i) o[i] = 0.f;
#pragma unroll
    for (int l = 0; l < NT; ++l) {
        const f32x4* vp = (const f32x4*)&V[l][c0];
        f32x4 a0 = vp[0], a1 = vp[1], a2 = vp[2], a3 = vp[3];
        float w = W[l];
#pragma unroll
        for (int i = 0; i < 4; ++i) {
            o[i]      = fmaf(w, a0[i], o[i]);
            o[4 + i]  = fmaf(w, a1[i], o[4 + i]);
            o[8 + i]  = fmaf(w, a2[i], o[8 + i]);
            o[12 + i] = fmaf(w, a3[i], o[12 + i]);
        }
    }
    uint_t ow[8];
#pragma unroll
    for (int i = 0; i < 8; ++i)
        ow[i] = (uint_t)f2b(o[2 * i]) | ((uint_t)f2b(o[2 * i + 1]) << 16);
    uint4* op = (uint4*)(Tbf + (size_t)bid * 4096 + row * 64 + c0);
    op[0] = make_uint4(ow[0], ow[1], ow[2], ow[3]);
    op[1] = make_uint4(ow[4], ow[5], ow[6], ow[7]);
}

// --- GEMM2: gpart[kc][b][m] = sum_{uv in chunk} O[b][.] psiB[m][.] ---------
// grid 256 = 4 bt x 64 kc; 4 waves split the 512-long K-chunk; LDS reduce.
__global__ __launch_bounds__(256) void gemm2_k(const ushort_t* __restrict__ Obf,
                                               const ushort_t* __restrict__ psiB,
                                               float* __restrict__ gpart) {
    __shared__ __align__(16) float Lg[64 * 68];    // [b 64][m 64] stride 68
    int bt = blockIdx.x & 3;
    int kc = blockIdx.x >> 2;          // 0..63
    int k = kc >> 3;
    int uv0 = (kc & 7) * 512;
    int tid = threadIdx.x, wave = tid >> 6, lane = tid & 63;
    int rowi = lane & 15, q = lane >> 4;

    f32x4 acc[4][4];
    const f32x4 zero = {0.f, 0.f, 0.f, 0.f};
    for (int ta = 0; ta < 4; ++ta)
        for (int tb = 0; tb < 4; ++tb) acc[ta][tb] = zero;

    for (int ks = 0; ks < 4; ++ks) {
        int off = uv0 + wave * 128 + ks * 32 + q * 8;
        bf16x8 a[4], bb[4];
        for (int ta = 0; ta < 4; ++ta)
            a[ta] = *(const bf16x8*)(psiB + (size_t)k * 262144 +
                                     (size_t)(ta * 16 + rowi) * 4096 + off);
        for (int tb = 0; tb < 4; ++tb)
            bb[tb] = *(const bf16x8*)(Obf +
                                      (size_t)(bt * 64 + tb * 16 + rowi) * 32768 +
                                      k * 4096 + off);
        for (int ta = 0; ta < 4; ++ta)
            for (int tb = 0; tb < 4; ++tb)
                acc[ta][tb] = __builtin_amdgcn_mfma_f32_16x16x32_bf16(
                    a[ta], bb[tb], acc[ta][tb], 0, 0, 0);
    }
    for (int w = 0; w < 4; ++w) {
        if (wave == w) {
            for (int ta = 0; ta < 4; ++ta)
                for (int tb = 0; tb < 4; ++tb) {
                    float* dst = &Lg[(tb * 16 + rowi) * 68 + ta * 16 + q * 4];
                    if (w == 0) *(f32x4*)dst = acc[ta][tb];
                    else {
                        f32x4 t = *(const f32x4*)dst;
                        t += acc[ta][tb];
                        *(f32x4*)dst = t;
                    }
                }
        }
        __syncthreads();
    }
    int b = tid >> 2, mq = tid & 3;
    float* gp = gpart + (size_t)kc * 16384 + (size_t)(bt * 64 + b) * 64 + mq * 16;
    const float* lp = &Lg[b * 68 + mq * 16];
    for (int i = 0; i < 4; ++i)
        *(f32x4*)(gp + 4 * i) = *(const f32x4*)(lp + 4 * i);
}

// --- FISTA: reduce 64 partials + prox step; maintain fp32 + bf16 state -----
__global__ __launch_bounds__(256) void fista_update(const float* __restrict__ gpart,
                                                    float* __restrict__ cb,
                                                    float* __restrict__ yb,
                                                    ushort_t* __restrict__ cbf,
                                                    ushort_t* __restrict__ ybf,
                                                    int iter) {
    int idx = blockIdx.x * 256 + threadIdx.x;
    float a0 = 0.f, a1 = 0.f, a2 = 0.f, a3 = 0.f;
#pragma unroll
    for (int p = 0; p < 64; p += 4) {
        a0 += gpart[(size_t)p * 16384 + idx];
        a1 += gpart[(size_t)(p + 1) * 16384 + idx];
        a2 += gpart[(size_t)(p + 2) * 16384 + idx];
        a3 += gpart[(size_t)(p + 3) * 16384 + idx];
    }
    float gv = (a0 + a1) + (a2 + a3);
    float t = 1.f;
    for (int s = 0; s < iter; ++s) t = 0.5f * (1.f + sqrtf(1.f + 4.f * t * t));
    float tn = 0.5f * (1.f + sqrtf(1.f + 4.f * t * t));
    float beta = (t - 1.f) / tn;
    float co = cb[idx], yo = yb[idx];
    float a = yo - 0.01f * gv;
    float thr = 0.01f * 0.05f;
    float cn = copysignf(fmaxf(fabsf(a) - thr, 0.f), a);
    float yn = cn + beta * (cn - co);
    cb[idx] = cn;
    yb[idx] = yn;
    cbf[idx] = f2b(cn);
    ybf[idx] = f2b(yn);
}

extern "C" void kernel_launch(void* const* d_in, const int* in_sizes, int n_in,
                              void* d_out, int out_size, void* d_ws, size_t ws_size,
                              hipStream_t stream) {
    const float* z0 = (const float*)d_in[0];
    const float* z1 = (const float*)d_in[1];
    const float* psi = (const float*)d_in[2];
    float* out = (float*)d_out;

    char* w = (char*)d_ws;
    ushort_t* TO    = (ushort_t*)(w);                 // 16,777,216  (T, then O)
    ushort_t* psiB  = (ushort_t*)(w + 16777216);      //  4,194,304
    ushort_t* psiT  = (ushort_t*)(w + 20971520);      //  4,194,304
    float*    gpart = (float*)(w + 25165824);         //  4,194,304  (64 partials)
    float*    cbuf  = (float*)(w + 29360128);         //     65,536
    float*    ybuf  = (float*)(w + 29425664);         //     65,536
    ushort_t* cbf   = (ushort_t*)(w + 29491200);      //     32,768
    ushort_t* ybf   = (ushort_t*)(w + 29523968);      //     32,768
    // total 29,556,736 B

    // prep converts psi AND zeroes c/y state (196608 B) -- no memset node
    prep_k<<<1024, 256, 0, stream>>>(psi, psiB, psiT, (uint4*)(w + 29360128));

    // iter 0: y=0 => T=0 => O = (z0-z1) z0^T directly (bit-identical)
    outer0_k<<<2048, 256, 0, stream>>>(z0, z1, TO);
    gemm2_k<<<256, 256, 0, stream>>>(TO, psiB, gpart);
    fista_update<<<64, 256, 0, stream>>>(gpart, cbuf, ybuf, cbf, ybf, 0);

    for (int it = 1; it < 20; ++it) {
        gemm1_k<<<1024, 256, 0, stream>>>(ybf, psiT, TO);
        krylov_k<5><<<2048, 256, 0, stream>>>(TO, z0, z1, nullptr);
        gemm2_k<<<256, 256, 0, stream>>>(TO, psiB, gpart);
        fista_update<<<64, 256, 0, stream>>>(gpart, cbuf, ybuf, cbf, ybf, it);
    }

    gemm1_k<<<1024, 256, 0, stream>>>(cbf, psiT, TO);
    krylov_k<8><<<2048, 256, 0, stream>>>(TO, z0, z1, out);
}

// Round 6
// 802.827 us; speedup vs baseline: 1.1095x; 1.0357x over previous
//
#include <hip/hip_runtime.h>
#include <hip/hip_bf16.h>

// ---------------------------------------------------------------------------
// TransportOperator: FISTA sparse coding through block-diag expm + transport.
// B=256, D=512, K=8, M=64, N=64.  20 FISTA iters, lr=0.01, lambda=0.05.
//
// R17 = R16 champion (831us: iter-0 outer-product shortcut) with ONE
// isolated change: gemm2 occupancy 4 -> 8 waves/CU at IDENTICAL traffic.
//   gemm2 (grid 256, block 512): 8 waves each take a 64-uv slice (2 ks),
//   8 private LDS partials (139.3 KB, 1 wg/CU), ONE barrier, 8-way pairwise
//   readback.  [R13's occupancy attempt doubled psiB traffic via bt-split
//   and lost; R15 never changed occupancy.  This is the clean test.]
// All other kernels byte-identical to R16.
// ---------------------------------------------------------------------------

typedef __attribute__((ext_vector_type(8))) short bf16x8;
typedef __attribute__((ext_vector_type(4))) float f32x4;
typedef unsigned short ushort_t;
typedef unsigned int uint_t;

__device__ __constant__ float INVF[20] = {
    1.0f, 1.0f, 0.5f, 1.6666666666666666e-1f, 4.1666666666666664e-2f,
    8.333333333333333e-3f, 1.3888888888888889e-3f, 1.984126984126984e-4f,
    2.48015873015873e-5f, 2.7557319223985893e-6f, 2.755731922398589e-7f,
    2.505210838544172e-8f, 2.08767569878681e-9f, 1.6059043836821613e-10f,
    1.1470745597729725e-11f, 7.647163731819816e-13f, 4.779477332387385e-14f,
    2.8114572543455206e-15f, 1.5619206968586225e-16f, 8.22063524662433e-18f};

__device__ __forceinline__ ushort_t f2b(float x) {
    uint_t u = __float_as_uint(x);
    uint_t r = u + 0x7FFFu + ((u >> 16) & 1u);   // RNE
    return (ushort_t)(r >> 16);
}
__device__ __forceinline__ float b2f(ushort_t h) {
    return __uint_as_float((uint_t)h << 16);
}

// quad sum via DPP (VALU pipe, no LDS ops)
__device__ __forceinline__ float qsum4(float s) {
    int a = __builtin_amdgcn_update_dpp(0, __float_as_int(s), 0xB1, 0xF, 0xF, true);
    s += __int_as_float(a);                       // xor 1
    int b = __builtin_amdgcn_update_dpp(0, __float_as_int(s), 0x4E, 0xF, 0xF, true);
    s += __int_as_float(b);                       // xor 2
    return s;
}

// --- one-time: psi -> psiB [k][m][uv], psiT [j][m]; zero c/y state ---------
__global__ __launch_bounds__(256) void prep_k(const float* __restrict__ psi,
                                              ushort_t* __restrict__ psiB,
                                              ushort_t* __restrict__ psiT,
                                              uint4* __restrict__ zero_base) {
    if (blockIdx.x < 48)   // zero 48*256*16 B = 196608 B (c,y fp32 + bf16)
        zero_base[blockIdx.x * 256 + threadIdx.x] = make_uint4(0, 0, 0, 0);
    int base = blockIdx.x * 2048 + threadIdx.x;
    for (int i = 0; i < 8; ++i) {
        int e = base + i * 256;                // e in [0, 2097152)
        float v = psi[e];
        ushort_t h = f2b(v);
        psiB[e] = h;
        int k = e >> 18;
        int r = e & 262143;
        int m = r >> 12;
        int uv = r & 4095;
        psiT[(size_t)k * 262144 + (size_t)uv * 64 + m] = h;
    }
}

// --- iter-0 shortcut: O[b,k] = (z0-z1) z0^T (T=0 => expm=I), bit-identical
// to champion gemm1+krylov<5,grad> at y=0.  grid 2048 = one wg per (b,k).
__global__ __launch_bounds__(256) void outer0_k(const float* __restrict__ z0,
                                                const float* __restrict__ z1,
                                                ushort_t* __restrict__ Tbf) {
    int bid = blockIdx.x;
    int b = bid >> 3, k = bid & 7;
    int tid = threadIdx.x;
    int row = tid >> 2, p = tid & 3, c0 = p * 16;
    const float* zb = z0 + (size_t)b * 512 + k * 64;
    float u = zb[row] - z1[(size_t)b * 512 + k * 64 + row];
    const f32x4* vp = (const f32x4*)(zb + c0);
    f32x4 v0 = vp[0], v1 = vp[1], v2 = vp[2], v3 = vp[3];
    float o[16];
#pragma unroll
    for (int i = 0; i < 4; ++i) {
        o[i]      = u * v0[i];
        o[4 + i]  = u * v1[i];
        o[8 + i]  = u * v2[i];
        o[12 + i] = u * v3[i];
    }
    uint_t ow[8];
#pragma unroll
    for (int i = 0; i < 8; ++i)
        ow[i] = (uint_t)f2b(o[2 * i]) | ((uint_t)f2b(o[2 * i + 1]) << 16);
    uint4* op = (uint4*)(Tbf + (size_t)bid * 4096 + row * 64 + c0);
    op[0] = make_uint4(ow[0], ow[1], ow[2], ow[3]);
    op[1] = make_uint4(ow[4], ow[5], ow[6], ow[7]);
}

// --- GEMM1: T[b][j] = sum_m y[b,m] * psiT[j,m].  D-rows <-> j. -------------
// grid 1024 = 512 j-windows x 2 b-halves (128 b).  18 KB LDS.
__global__ __launch_bounds__(256) void gemm1_k(const ushort_t* __restrict__ ybf,
                                               const ushort_t* __restrict__ psiT,
                                               ushort_t* __restrict__ Tbf) {
    __shared__ __align__(16) ushort_t Ls[128 * 72];   // [b 128][j 64] swizzled
    int wg = blockIdx.x;
    int j0 = (wg & 511) * 64;
    int bt = wg >> 9;                   // 0..1
    int tid = threadIdx.x;
    int wave = tid >> 6, lane = tid & 63;
    int rowi = lane & 15, q = lane >> 4;
    int b0w = bt * 128 + wave * 32;

    f32x4 acc[4][2];
    const f32x4 zero = {0.f, 0.f, 0.f, 0.f};
    for (int ta = 0; ta < 4; ++ta)
        for (int tb = 0; tb < 2; ++tb) acc[ta][tb] = zero;

    for (int ks = 0; ks < 2; ++ks) {
        bf16x8 a[4], bb[2];
        for (int ta = 0; ta < 4; ++ta)
            a[ta] = *(const bf16x8*)(psiT + (size_t)(j0 + ta * 16 + rowi) * 64 +
                                     ks * 32 + q * 8);
        for (int tb = 0; tb < 2; ++tb)
            bb[tb] = *(const bf16x8*)(ybf + (size_t)(b0w + tb * 16 + rowi) * 64 +
                                      ks * 32 + q * 8);
        for (int ta = 0; ta < 4; ++ta)
            for (int tb = 0; tb < 2; ++tb)
                acc[ta][tb] = __builtin_amdgcn_mfma_f32_16x16x32_bf16(
                    a[ta], bb[tb], acc[ta][tb], 0, 0, 0);
    }
    for (int ta = 0; ta < 4; ++ta)
        for (int tb = 0; tb < 2; ++tb) {
            int bl = wave * 32 + tb * 16 + rowi;      // local b in [0,128)
            int jl = ta * 16 + q * 4;
            uint_t lo = (uint_t)f2b(acc[ta][tb][0]) | ((uint_t)f2b(acc[ta][tb][1]) << 16);
            uint_t hi = (uint_t)f2b(acc[ta][tb][2]) | ((uint_t)f2b(acc[ta][tb][3]) << 16);
            int idx = bl * 72 + ((((jl >> 3) + 2 * bl) & 7) << 3) + (jl & 7);
            *(uint2*)&Ls[idx] = make_uint2(lo, hi);
        }
    __syncthreads();
    for (int pass = 0; pass < 4; ++pass) {
        int b = pass * 32 + (tid >> 3);               // local b
        int ch = tid & 7;
        uint4 v = *(const uint4*)&Ls[b * 72 + ch * 8];
        int x = (ch - 2 * b) & 7;
        *(uint4*)(Tbf + (size_t)(bt * 128 + b) * 32768 + j0 + x * 8) = v;
    }
}

// --- Krylov: per (b,k); T in registers; grad mode writes O over T. ---------
template <int NT>
__global__ __launch_bounds__(256) void krylov_k(ushort_t* __restrict__ Tbf,
                                                const float* __restrict__ z0,
                                                const float* __restrict__ z1,
                                                float* __restrict__ out) {
    __shared__ float V[NT][64];
    __shared__ float U[NT][64];
    __shared__ float zz[64];
    int bid = blockIdx.x;
    int b = bid >> 3, k = bid & 7;
    int tid = threadIdx.x;
    int row = tid >> 2, p = tid & 3, c0 = p * 16;
    bool grad = (out == nullptr);

    const ushort_t* tbase = Tbf + (size_t)bid * 4096;
    float rowT[16];
    {
        uint4 ra = *(const uint4*)(tbase + row * 64 + c0);
        uint4 rb = *(const uint4*)(tbase + row * 64 + c0 + 8);
        uint_t wv[8] = {ra.x, ra.y, ra.z, ra.w, rb.x, rb.y, rb.z, rb.w};
        for (int i = 0; i < 8; ++i) {
            rowT[2 * i]     = __uint_as_float(wv[i] << 16);
            rowT[2 * i + 1] = __uint_as_float(wv[i] & 0xFFFF0000u);
        }
    }
    float colT[16];
    if (grad) {
#pragma unroll
        for (int i = 0; i < 16; ++i) colT[i] = b2f(tbase[(c0 + i) * 64 + row]);
    }
    if (tid < 64) {
        V[0][tid] = z0[(size_t)b * 512 + k * 64 + tid];
        zz[tid]   = z1[(size_t)b * 512 + k * 64 + tid];
    }
    __syncthreads();

    for (int l = 1; l < NT; ++l) {
        const f32x4* vp = (const f32x4*)&V[l - 1][c0];
        f32x4 v0 = vp[0], v1 = vp[1], v2 = vp[2], v3 = vp[3];
        float s0 = 0.f, s1 = 0.f, s2 = 0.f, s3 = 0.f;
#pragma unroll
        for (int i = 0; i < 4; ++i) {
            s0 = fmaf(rowT[i], v0[i], s0);
            s1 = fmaf(rowT[4 + i], v1[i], s1);
            s2 = fmaf(rowT[8 + i], v2[i], s2);
            s3 = fmaf(rowT[12 + i], v3[i], s3);
        }
        float s = qsum4((s0 + s1) + (s2 + s3));
        if (p == 0) V[l][row] = s;
        __syncthreads();
    }

    if (!grad) {
        if (tid < 64) {
            float zh = 0.f;
#pragma unroll
            for (int l = 0; l < NT; ++l) zh = fmaf(INVF[l], V[l][tid], zh);
            out[(size_t)b * 512 + k * 64 + tid] = zh;
        }
        return;
    }

    if (tid < 64) {
        float zh = 0.f;
#pragma unroll
        for (int l = 0; l < NT; ++l) zh = fmaf(INVF[l], V[l][tid], zh);
        U[0][tid] = zh - zz[tid];
    }
    __syncthreads();

    for (int j = 1; j < NT; ++j) {
        const f32x4* up = (const f32x4*)&U[j - 1][c0];
        f32x4 u0 = up[0], u1 = up[1], u2 = up[2], u3 = up[3];
        float s0 = 0.f, s1 = 0.f, s2 = 0.f, s3 = 0.f;
#pragma unroll
        for (int i = 0; i < 4; ++i) {
            s0 = fmaf(colT[i], u0[i], s0);
            s1 = fmaf(colT[4 + i], u1[i], s1);
            s2 = fmaf(colT[8 + i], u2[i], s2);
            s3 = fmaf(colT[12 + i], u3[i], s3);
        }
        float s = qsum4((s0 + s1) + (s2 + s3));
        if (p == 0) U[j][row] = s;
        __syncthreads();
    }

    float W[NT];
#pragma unroll
    for (int l = 0; l < NT; ++l) {
        float w = 0.f;
#pragma unroll
        for (int j = 0; j < NT; ++j) w = fmaf(INVF[j + l + 1], U[j][row], w);
        W[l] = w;
    }
    float o[16];
#pragma unroll
    for (int i = 0; i < 16; ++i) o[i] = 0.f;
#pragma unroll
    for (int l = 0; l < NT; ++l) {
        const f32x4* vp = (const f32x4*)&V[l][c0];
        f32x4 a0 = vp[0], a1 = vp[1], a2 = vp[2], a3 = vp[3];
        float w = W[l];
#pragma unroll
        for (int i = 0; i < 4; ++i) {
            o[i]      = fmaf(w, a0[i], o[i]);
            o[4 + i]  = fmaf(w, a1[i], o[4 + i]);
            o[8 + i]  = fmaf(w, a2[i], o[8 + i]);
            o[12 + i] = fmaf(w, a3[i], o[12 + i]);
        }
    }
    uint_t ow[8];
#pragma unroll
    for (int i = 0; i < 8; ++i)
        ow[i] = (uint_t)f2b(o[2 * i]) | ((uint_t)f2b(o[2 * i + 1]) << 16);
    uint4* op = (uint4*)(Tbf + (size_t)bid * 4096 + row * 64 + c0);
    op[0] = make_uint4(ow[0], ow[1], ow[2], ow[3]);
    op[1] = make_uint4(ow[4], ow[5], ow[6], ow[7]);
}

// --- GEMM2: gpart[kc][b][m] = sum_{uv in chunk} O[b][.] psiB[m][.] ---------
// grid 256 = 4 bt x 64 kc (champion tiling/traffic); block 512 = 8 waves,
// each wave takes a 64-uv slice (2 ks) -> 8 waves/CU latency hiding (was 4).
// 8 private LDS partials (139.3 KB, 1 wg/CU), ONE barrier, pairwise reduce.
__global__ __launch_bounds__(512) void gemm2_k(const ushort_t* __restrict__ Obf,
                                               const ushort_t* __restrict__ psiB,
                                               float* __restrict__ gpart) {
    __shared__ __align__(16) float Lg[8][64 * 68];    // [w][b 64][m 64] str 68
    int bt = blockIdx.x & 3;
    int kc = blockIdx.x >> 2;          // 0..63
    int k = kc >> 3;
    int uv0 = (kc & 7) * 512;
    int tid = threadIdx.x, wave = tid >> 6, lane = tid & 63;
    int rowi = lane & 15, q = lane >> 4;

    f32x4 acc[4][4];
    const f32x4 zero = {0.f, 0.f, 0.f, 0.f};
    for (int ta = 0; ta < 4; ++ta)
        for (int tb = 0; tb < 4; ++tb) acc[ta][tb] = zero;

    for (int ks = 0; ks < 2; ++ks) {
        int off = uv0 + wave * 64 + ks * 32 + q * 8;
        bf16x8 a[4], bb[4];
        for (int ta = 0; ta < 4; ++ta)
            a[ta] = *(const bf16x8*)(psiB + (size_t)k * 262144 +
                                     (size_t)(ta * 16 + rowi) * 4096 + off);
        for (int tb = 0; tb < 4; ++tb)
            bb[tb] = *(const bf16x8*)(Obf +
                                      (size_t)(bt * 64 + tb * 16 + rowi) * 32768 +
                                      k * 4096 + off);
        for (int ta = 0; ta < 4; ++ta)
            for (int tb = 0; tb < 4; ++tb)
                acc[ta][tb] = __builtin_amdgcn_mfma_f32_16x16x32_bf16(
                    a[ta], bb[tb], acc[ta][tb], 0, 0, 0);
    }
    float* lw = &Lg[wave][0];
    for (int ta = 0; ta < 4; ++ta)
        for (int tb = 0; tb < 4; ++tb)
            *(f32x4*)&lw[(tb * 16 + rowi) * 68 + ta * 16 + q * 4] = acc[ta][tb];
    __syncthreads();

    int b = tid >> 3, m0 = (tid & 7) * 8;            // 64 b x 8 m per thread
    const float* l0 = &Lg[0][b * 68 + m0];
    float* gp = gpart + (size_t)kc * 16384 + (size_t)(bt * 64 + b) * 64 + m0;
#pragma unroll
    for (int i = 0; i < 2; ++i) {
        f32x4 s0 = *(const f32x4*)(l0 + 0 * 4352 + 4 * i);
        f32x4 s1 = *(const f32x4*)(l0 + 1 * 4352 + 4 * i);
        f32x4 s2 = *(const f32x4*)(l0 + 2 * 4352 + 4 * i);
        f32x4 s3 = *(const f32x4*)(l0 + 3 * 4352 + 4 * i);
        f32x4 s4 = *(const f32x4*)(l0 + 4 * 4352 + 4 * i);
        f32x4 s5 = *(const f32x4*)(l0 + 5 * 4352 + 4 * i);
        f32x4 s6 = *(const f32x4*)(l0 + 6 * 4352 + 4 * i);
        f32x4 s7 = *(const f32x4*)(l0 + 7 * 4352 + 4 * i);
        f32x4 s = ((s0 + s1) + (s2 + s3)) + ((s4 + s5) + (s6 + s7));
        *(f32x4*)(gp + 4 * i) = s;
    }
}

// --- FISTA: reduce 64 partials + prox step; maintain fp32 + bf16 state -----
__global__ __launch_bounds__(256) void fista_update(const float* __restrict__ gpart,
                                                    float* __restrict__ cb,
                                                    float* __restrict__ yb,
                                                    ushort_t* __restrict__ cbf,
                                                    ushort_t* __restrict__ ybf,
                                                    int iter) {
    int idx = blockIdx.x * 256 + threadIdx.x;
    float a0 = 0.f, a1 = 0.f, a2 = 0.f, a3 = 0.f;
#pragma unroll
    for (int p = 0; p < 64; p += 4) {
        a0 += gpart[(size_t)p * 16384 + idx];
        a1 += gpart[(size_t)(p + 1) * 16384 + idx];
        a2 += gpart[(size_t)(p + 2) * 16384 + idx];
        a3 += gpart[(size_t)(p + 3) * 16384 + idx];
    }
    float gv = (a0 + a1) + (a2 + a3);
    float t = 1.f;
    for (int s = 0; s < iter; ++s) t = 0.5f * (1.f + sqrtf(1.f + 4.f * t * t));
    float tn = 0.5f * (1.f + sqrtf(1.f + 4.f * t * t));
    float beta = (t - 1.f) / tn;
    float co = cb[idx], yo = yb[idx];
    float a = yo - 0.01f * gv;
    float thr = 0.01f * 0.05f;
    float cn = copysignf(fmaxf(fabsf(a) - thr, 0.f), a);
    float yn = cn + beta * (cn - co);
    cb[idx] = cn;
    yb[idx] = yn;
    cbf[idx] = f2b(cn);
    ybf[idx] = f2b(yn);
}

extern "C" void kernel_launch(void* const* d_in, const int* in_sizes, int n_in,
                              void* d_out, int out_size, void* d_ws, size_t ws_size,
                              hipStream_t stream) {
    const float* z0 = (const float*)d_in[0];
    const float* z1 = (const float*)d_in[1];
    const float* psi = (const float*)d_in[2];
    float* out = (float*)d_out;

    char* w = (char*)d_ws;
    ushort_t* TO    = (ushort_t*)(w);                 // 16,777,216  (T, then O)
    ushort_t* psiB  = (ushort_t*)(w + 16777216);      //  4,194,304
    ushort_t* psiT  = (ushort_t*)(w + 20971520);      //  4,194,304
    float*    gpart = (float*)(w + 25165824);         //  4,194,304  (64 partials)
    float*    cbuf  = (float*)(w + 29360128);         //     65,536
    float*    ybuf  = (float*)(w + 29425664);         //     65,536
    ushort_t* cbf   = (ushort_t*)(w + 29491200);      //     32,768
    ushort_t* ybf   = (ushort_t*)(w + 29523968);      //     32,768
    // total 29,556,736 B

    // prep converts psi AND zeroes c/y state (196608 B) -- no memset node
    prep_k<<<1024, 256, 0, stream>>>(psi, psiB, psiT, (uint4*)(w + 29360128));

    // iter 0: y=0 => T=0 => O = (z0-z1) z0^T directly (bit-identical)
    outer0_k<<<2048, 256, 0, stream>>>(z0, z1, TO);
    gemm2_k<<<256, 512, 0, stream>>>(TO, psiB, gpart);
    fista_update<<<64, 256, 0, stream>>>(gpart, cbuf, ybuf, cbf, ybf, 0);

    for (int it = 1; it < 20; ++it) {
        gemm1_k<<<1024, 256, 0, stream>>>(ybf, psiT, TO);
        krylov_k<5><<<2048, 256, 0, stream>>>(TO, z0, z1, nullptr);
        gemm2_k<<<256, 512, 0, stream>>>(TO, psiB, gpart);
        fista_update<<<64, 256, 0, stream>>>(gpart, cbuf, ybuf, cbf, ybf, it);
    }

    gemm1_k<<<1024, 256, 0, stream>>>(cbf, psiT, TO);
    krylov_k<8><<<2048, 256, 0, stream>>>(TO, z0, z1, out);
}

// Round 7
// 794.265 us; speedup vs baseline: 1.1215x; 1.0108x over previous
//
#include <hip/hip_runtime.h>
#include <hip/hip_bf16.h>

// ---------------------------------------------------------------------------
// TransportOperator: FISTA sparse coding through block-diag expm + transport.
// B=256, D=512, K=8, M=64, N=64.  20 FISTA iters, lr=0.01, lambda=0.05.
//
// R18 = R17 champion (802us) with the PROLOGUE rebuilt; 19-iter loop and all
// per-iter kernels byte-identical to R17.
//   prep0_k (grid 2560 = 2048 outer0-role + 512 prep-role):
//     - outer0 role: O[b,k] = (z0-z1) z0^T  (iter-0 shortcut, verbatim).
//     - prep role: psiB linear convert (coalesced) + psiT via TILE TRANSPOSE:
//       thread gathers 16 psi values down a column (every 64B psi line fully
//       consumed by 16 lanes) and writes 32B packed psiT rows -- replaces
//       champion's 2M scattered u16 stores (stride-128B, 64x transaction
//       amplification).  Bit-identical values (same f2b, same mapping).
//     - saves one dispatch + overlaps outer0 exec under prep.
// Loop: 19x {gemm1, krylov<5>, gemm2(512thr 8-wave), fista}; final
// gemm1+krylov<8>.  gemm2 is R17's 8-wave variant (confirmed -29us).
// ---------------------------------------------------------------------------

typedef __attribute__((ext_vector_type(8))) short bf16x8;
typedef __attribute__((ext_vector_type(4))) float f32x4;
typedef unsigned short ushort_t;
typedef unsigned int uint_t;

__device__ __constant__ float INVF[20] = {
    1.0f, 1.0f, 0.5f, 1.6666666666666666e-1f, 4.1666666666666664e-2f,
    8.333333333333333e-3f, 1.3888888888888889e-3f, 1.984126984126984e-4f,
    2.48015873015873e-5f, 2.7557319223985893e-6f, 2.755731922398589e-7f,
    2.505210838544172e-8f, 2.08767569878681e-9f, 1.6059043836821613e-10f,
    1.1470745597729725e-11f, 7.647163731819816e-13f, 4.779477332387385e-14f,
    2.8114572543455206e-15f, 1.5619206968586225e-16f, 8.22063524662433e-18f};

__device__ __forceinline__ ushort_t f2b(float x) {
    uint_t u = __float_as_uint(x);
    uint_t r = u + 0x7FFFu + ((u >> 16) & 1u);   // RNE
    return (ushort_t)(r >> 16);
}
__device__ __forceinline__ float b2f(ushort_t h) {
    return __uint_as_float((uint_t)h << 16);
}

// quad sum via DPP (VALU pipe, no LDS ops)
__device__ __forceinline__ float qsum4(float s) {
    int a = __builtin_amdgcn_update_dpp(0, __float_as_int(s), 0xB1, 0xF, 0xF, true);
    s += __int_as_float(a);                       // xor 1
    int b = __builtin_amdgcn_update_dpp(0, __float_as_int(s), 0x4E, 0xF, 0xF, true);
    s += __int_as_float(b);                       // xor 2
    return s;
}

// --- fused prologue: outer0 (wg<2048) + prep (wg>=2048) --------------------
// outer0: O[b,k] = (z0-z1) z0^T (T=0 => expm=I at it=0), bit-identical to
// champion gemm1+krylov<5,grad> at y=0.
// prep: psiB[e]=f2b(psi[e]) linear; psiT[k][uv][m]=f2b(psi[k][m][uv]) via
// per-wg 64x64 tile transpose (coalesced reads AND writes); zero c/y state.
__global__ __launch_bounds__(256) void prep0_k(const float* __restrict__ psi,
                                               ushort_t* __restrict__ psiB,
                                               ushort_t* __restrict__ psiT,
                                               uint4* __restrict__ zero_base,
                                               const float* __restrict__ z0,
                                               const float* __restrict__ z1,
                                               ushort_t* __restrict__ Tbf) {
    int wg = blockIdx.x;
    int tid = threadIdx.x;
    if (wg < 2048) {
        // ---- outer0 role (verbatim R16/R17 outer0_k) ----
        int bid = wg;
        int b = bid >> 3, k = bid & 7;
        int row = tid >> 2, p = tid & 3, c0 = p * 16;
        const float* zb = z0 + (size_t)b * 512 + k * 64;
        float u = zb[row] - z1[(size_t)b * 512 + k * 64 + row];
        const f32x4* vp = (const f32x4*)(zb + c0);
        f32x4 v0 = vp[0], v1 = vp[1], v2 = vp[2], v3 = vp[3];
        float o[16];
#pragma unroll
        for (int i = 0; i < 4; ++i) {
            o[i]      = u * v0[i];
            o[4 + i]  = u * v1[i];
            o[8 + i]  = u * v2[i];
            o[12 + i] = u * v3[i];
        }
        uint_t ow[8];
#pragma unroll
        for (int i = 0; i < 8; ++i)
            ow[i] = (uint_t)f2b(o[2 * i]) | ((uint_t)f2b(o[2 * i + 1]) << 16);
        uint4* op = (uint4*)(Tbf + (size_t)bid * 4096 + row * 64 + c0);
        op[0] = make_uint4(ow[0], ow[1], ow[2], ow[3]);
        op[1] = make_uint4(ow[4], ow[5], ow[6], ow[7]);
        return;
    }
    int t = wg - 2048;                 // 0..511
    if (t < 48)   // zero 48*256*16 B = 196608 B (c,y fp32 + bf16)
        zero_base[t * 256 + tid] = make_uint4(0, 0, 0, 0);
    // psiB: linear coalesced convert, 4096 elems per wg
    int base = t * 4096 + tid;
#pragma unroll
    for (int i = 0; i < 16; ++i) {
        int e = base + i * 256;                // e in [0, 2097152)
        psiB[e] = f2b(psi[e]);
    }
    // psiT: 64x64 tile transpose.  tile (k, uvb); thread (uv=tid>>2, g=tid&3)
    // gathers psi[k][g*16+i][uv0+uv] for i=0..15 (each 64B psi line consumed
    // by 16 lanes), packs, writes psiT[k][uv0+uv][g*16..+15] as 2x uint4.
    int k = t >> 6, uvb = t & 63;
    int uv = tid >> 2, g = tid & 3;
    size_t pbase = (size_t)k * 262144 + (size_t)(g * 16) * 4096 + uvb * 64 + uv;
    float v[16];
#pragma unroll
    for (int i = 0; i < 16; ++i) v[i] = psi[pbase + (size_t)i * 4096];
    uint_t ow[8];
#pragma unroll
    for (int i = 0; i < 8; ++i)
        ow[i] = (uint_t)f2b(v[2 * i]) | ((uint_t)f2b(v[2 * i + 1]) << 16);
    uint4* op = (uint4*)(psiT + (size_t)k * 262144 +
                         (size_t)(uvb * 64 + uv) * 64 + g * 16);
    op[0] = make_uint4(ow[0], ow[1], ow[2], ow[3]);
    op[1] = make_uint4(ow[4], ow[5], ow[6], ow[7]);
}

// --- GEMM1: T[b][j] = sum_m y[b,m] * psiT[j,m].  D-rows <-> j. -------------
// grid 1024 = 512 j-windows x 2 b-halves (128 b).  18 KB LDS.
__global__ __launch_bounds__(256) void gemm1_k(const ushort_t* __restrict__ ybf,
                                               const ushort_t* __restrict__ psiT,
                                               ushort_t* __restrict__ Tbf) {
    __shared__ __align__(16) ushort_t Ls[128 * 72];   // [b 128][j 64] swizzled
    int wg = blockIdx.x;
    int j0 = (wg & 511) * 64;
    int bt = wg >> 9;                   // 0..1
    int tid = threadIdx.x;
    int wave = tid >> 6, lane = tid & 63;
    int rowi = lane & 15, q = lane >> 4;
    int b0w = bt * 128 + wave * 32;

    f32x4 acc[4][2];
    const f32x4 zero = {0.f, 0.f, 0.f, 0.f};
    for (int ta = 0; ta < 4; ++ta)
        for (int tb = 0; tb < 2; ++tb) acc[ta][tb] = zero;

    for (int ks = 0; ks < 2; ++ks) {
        bf16x8 a[4], bb[2];
        for (int ta = 0; ta < 4; ++ta)
            a[ta] = *(const bf16x8*)(psiT + (size_t)(j0 + ta * 16 + rowi) * 64 +
                                     ks * 32 + q * 8);
        for (int tb = 0; tb < 2; ++tb)
            bb[tb] = *(const bf16x8*)(ybf + (size_t)(b0w + tb * 16 + rowi) * 64 +
                                      ks * 32 + q * 8);
        for (int ta = 0; ta < 4; ++ta)
            for (int tb = 0; tb < 2; ++tb)
                acc[ta][tb] = __builtin_amdgcn_mfma_f32_16x16x32_bf16(
                    a[ta], bb[tb], acc[ta][tb], 0, 0, 0);
    }
    for (int ta = 0; ta < 4; ++ta)
        for (int tb = 0; tb < 2; ++tb) {
            int bl = wave * 32 + tb * 16 + rowi;      // local b in [0,128)
            int jl = ta * 16 + q * 4;
            uint_t lo = (uint_t)f2b(acc[ta][tb][0]) | ((uint_t)f2b(acc[ta][tb][1]) << 16);
            uint_t hi = (uint_t)f2b(acc[ta][tb][2]) | ((uint_t)f2b(acc[ta][tb][3]) << 16);
            int idx = bl * 72 + ((((jl >> 3) + 2 * bl) & 7) << 3) + (jl & 7);
            *(uint2*)&Ls[idx] = make_uint2(lo, hi);
        }
    __syncthreads();
    for (int pass = 0; pass < 4; ++pass) {
        int b = pass * 32 + (tid >> 3);               // local b
        int ch = tid & 7;
        uint4 v = *(const uint4*)&Ls[b * 72 + ch * 8];
        int x = (ch - 2 * b) & 7;
        *(uint4*)(Tbf + (size_t)(bt * 128 + b) * 32768 + j0 + x * 8) = v;
    }
}

// --- Krylov: per (b,k); T in registers; grad mode writes O over T. ---------
template <int NT>
__global__ __launch_bounds__(256) void krylov_k(ushort_t* __restrict__ Tbf,
                                                const float* __restrict__ z0,
                                                const float* __restrict__ z1,
                                                float* __restrict__ out) {
    __shared__ float V[NT][64];
    __shared__ float U[NT][64];
    __shared__ float zz[64];
    int bid = blockIdx.x;
    int b = bid >> 3, k = bid & 7;
    int tid = threadIdx.x;
    int row = tid >> 2, p = tid & 3, c0 = p * 16;
    bool grad = (out == nullptr);

    const ushort_t* tbase = Tbf + (size_t)bid * 4096;
    float rowT[16];
    {
        uint4 ra = *(const uint4*)(tbase + row * 64 + c0);
        uint4 rb = *(const uint4*)(tbase + row * 64 + c0 + 8);
        uint_t wv[8] = {ra.x, ra.y, ra.z, ra.w, rb.x, rb.y, rb.z, rb.w};
        for (int i = 0; i < 8; ++i) {
            rowT[2 * i]     = __uint_as_float(wv[i] << 16);
            rowT[2 * i + 1] = __uint_as_float(wv[i] & 0xFFFF0000u);
        }
    }
    float colT[16];
    if (grad) {
#pragma unroll
        for (int i = 0; i < 16; ++i) colT[i] = b2f(tbase[(c0 + i) * 64 + row]);
    }
    if (tid < 64) {
        V[0][tid] = z0[(size_t)b * 512 + k * 64 + tid];
        zz[tid]   = z1[(size_t)b * 512 + k * 64 + tid];
    }
    __syncthreads();

    for (int l = 1; l < NT; ++l) {
        const f32x4* vp = (const f32x4*)&V[l - 1][c0];
        f32x4 v0 = vp[0], v1 = vp[1], v2 = vp[2], v3 = vp[3];
        float s0 = 0.f, s1 = 0.f, s2 = 0.f, s3 = 0.f;
#pragma unroll
        for (int i = 0; i < 4; ++i) {
            s0 = fmaf(rowT[i], v0[i], s0);
            s1 = fmaf(rowT[4 + i], v1[i], s1);
            s2 = fmaf(rowT[8 + i], v2[i], s2);
            s3 = fmaf(rowT[12 + i], v3[i], s3);
        }
        float s = qsum4((s0 + s1) + (s2 + s3));
        if (p == 0) V[l][row] = s;
        __syncthreads();
    }

    if (!grad) {
        if (tid < 64) {
            float zh = 0.f;
#pragma unroll
            for (int l = 0; l < NT; ++l) zh = fmaf(INVF[l], V[l][tid], zh);
            out[(size_t)b * 512 + k * 64 + tid] = zh;
        }
        return;
    }

    if (tid < 64) {
        float zh = 0.f;
#pragma unroll
        for (int l = 0; l < NT; ++l) zh = fmaf(INVF[l], V[l][tid], zh);
        U[0][tid] = zh - zz[tid];
    }
    __syncthreads();

    for (int j = 1; j < NT; ++j) {
        const f32x4* up = (const f32x4*)&U[j - 1][c0];
        f32x4 u0 = up[0], u1 = up[1], u2 = up[2], u3 = up[3];
        float s0 = 0.f, s1 = 0.f, s2 = 0.f, s3 = 0.f;
#pragma unroll
        for (int i = 0; i < 4; ++i) {
            s0 = fmaf(colT[i], u0[i], s0);
            s1 = fmaf(colT[4 + i], u1[i], s1);
            s2 = fmaf(colT[8 + i], u2[i], s2);
            s3 = fmaf(colT[12 + i], u3[i], s3);
        }
        float s = qsum4((s0 + s1) + (s2 + s3));
        if (p == 0) U[j][row] = s;
        __syncthreads();
    }

    float W[NT];
#pragma unroll
    for (int l = 0; l < NT; ++l) {
        float w = 0.f;
#pragma unroll
        for (int j = 0; j < NT; ++j) w = fmaf(INVF[j + l + 1], U[j][row], w);
        W[l] = w;
    }
    float o[16];
#pragma unroll
    for (int i = 0; i < 16; ++i) o[i] = 0.f;
#pragma unroll
    for (int l = 0; l < NT; ++l) {
        const f32x4* vp = (const f32x4*)&V[l][c0];
        f32x4 a0 = vp[0], a1 = vp[1], a2 = vp[2], a3 = vp[3];
        float w = W[l];
#pragma unroll
        for (int i = 0; i < 4; ++i) {
            o[i]      = fmaf(w, a0[i], o[i]);
            o[4 + i]  = fmaf(w, a1[i], o[4 + i]);
            o[8 + i]  = fmaf(w, a2[i], o[8 + i]);
            o[12 + i] = fmaf(w, a3[i], o[12 + i]);
        }
    }
    uint_t ow[8];
#pragma unroll
    for (int i = 0; i < 8; ++i)
        ow[i] = (uint_t)f2b(o[2 * i]) | ((uint_t)f2b(o[2 * i + 1]) << 16);
    uint4* op = (uint4*)(Tbf + (size_t)bid * 4096 + row * 64 + c0);
    op[0] = make_uint4(ow[0], ow[1], ow[2], ow[3]);
    op[1] = make_uint4(ow[4], ow[5], ow[6], ow[7]);
}

// --- GEMM2: gpart[kc][b][m] = sum_{uv in chunk} O[b][.] psiB[m][.] ---------
// grid 256 = 4 bt x 64 kc (champion tiling/traffic); block 512 = 8 waves,
// each wave takes a 64-uv slice (2 ks) -> 8 waves/CU latency hiding (was 4).
// 8 private LDS partials (139.3 KB, 1 wg/CU), ONE barrier, pairwise reduce.
__global__ __launch_bounds__(512) void gemm2_k(const ushort_t* __restrict__ Obf,
                                               const ushort_t* __restrict__ psiB,
                                               float* __restrict__ gpart) {
    __shared__ __align__(16) float Lg[8][64 * 68];    // [w][b 64][m 64] str 68
    int bt = blockIdx.x & 3;
    int kc = blockIdx.x >> 2;          // 0..63
    int k = kc >> 3;
    int uv0 = (kc & 7) * 512;
    int tid = threadIdx.x, wave = tid >> 6, lane = tid & 63;
    int rowi = lane & 15, q = lane >> 4;

    f32x4 acc[4][4];
    const f32x4 zero = {0.f, 0.f, 0.f, 0.f};
    for (int ta = 0; ta < 4; ++ta)
        for (int tb = 0; tb < 4; ++tb) acc[ta][tb] = zero;

    for (int ks = 0; ks < 2; ++ks) {
        int off = uv0 + wave * 64 + ks * 32 + q * 8;
        bf16x8 a[4], bb[4];
        for (int ta = 0; ta < 4; ++ta)
            a[ta] = *(const bf16x8*)(psiB + (size_t)k * 262144 +
                                     (size_t)(ta * 16 + rowi) * 4096 + off);
        for (int tb = 0; tb < 4; ++tb)
            bb[tb] = *(const bf16x8*)(Obf +
                                      (size_t)(bt * 64 + tb * 16 + rowi) * 32768 +
                                      k * 4096 + off);
        for (int ta = 0; ta < 4; ++ta)
            for (int tb = 0; tb < 4; ++tb)
                acc[ta][tb] = __builtin_amdgcn_mfma_f32_16x16x32_bf16(
                    a[ta], bb[tb], acc[ta][tb], 0, 0, 0);
    }
    float* lw = &Lg[wave][0];
    for (int ta = 0; ta < 4; ++ta)
        for (int tb = 0; tb < 4; ++tb)
            *(f32x4*)&lw[(tb * 16 + rowi) * 68 + ta * 16 + q * 4] = acc[ta][tb];
    __syncthreads();

    int b = tid >> 3, m0 = (tid & 7) * 8;            // 64 b x 8 m per thread
    const float* l0 = &Lg[0][b * 68 + m0];
    float* gp = gpart + (size_t)kc * 16384 + (size_t)(bt * 64 + b) * 64 + m0;
#pragma unroll
    for (int i = 0; i < 2; ++i) {
        f32x4 s0 = *(const f32x4*)(l0 + 0 * 4352 + 4 * i);
        f32x4 s1 = *(const f32x4*)(l0 + 1 * 4352 + 4 * i);
        f32x4 s2 = *(const f32x4*)(l0 + 2 * 4352 + 4 * i);
        f32x4 s3 = *(const f32x4*)(l0 + 3 * 4352 + 4 * i);
        f32x4 s4 = *(const f32x4*)(l0 + 4 * 4352 + 4 * i);
        f32x4 s5 = *(const f32x4*)(l0 + 5 * 4352 + 4 * i);
        f32x4 s6 = *(const f32x4*)(l0 + 6 * 4352 + 4 * i);
        f32x4 s7 = *(const f32x4*)(l0 + 7 * 4352 + 4 * i);
        f32x4 s = ((s0 + s1) + (s2 + s3)) + ((s4 + s5) + (s6 + s7));
        *(f32x4*)(gp + 4 * i) = s;
    }
}

// --- FISTA: reduce 64 partials + prox step; maintain fp32 + bf16 state -----
__global__ __launch_bounds__(256) void fista_update(const float* __restrict__ gpart,
                                                    float* __restrict__ cb,
                                                    float* __restrict__ yb,
                                                    ushort_t* __restrict__ cbf,
                                                    ushort_t* __restrict__ ybf,
                                                    int iter) {
    int idx = blockIdx.x * 256 + threadIdx.x;
    float a0 = 0.f, a1 = 0.f, a2 = 0.f, a3 = 0.f;
#pragma unroll
    for (int p = 0; p < 64; p += 4) {
        a0 += gpart[(size_t)p * 16384 + idx];
        a1 += gpart[(size_t)(p + 1) * 16384 + idx];
        a2 += gpart[(size_t)(p + 2) * 16384 + idx];
        a3 += gpart[(size_t)(p + 3) * 16384 + idx];
    }
    float gv = (a0 + a1) + (a2 + a3);
    float t = 1.f;
    for (int s = 0; s < iter; ++s) t = 0.5f * (1.f + sqrtf(1.f + 4.f * t * t));
    float tn = 0.5f * (1.f + sqrtf(1.f + 4.f * t * t));
    float beta = (t - 1.f) / tn;
    float co = cb[idx], yo = yb[idx];
    float a = yo - 0.01f * gv;
    float thr = 0.01f * 0.05f;
    float cn = copysignf(fmaxf(fabsf(a) - thr, 0.f), a);
    float yn = cn + beta * (cn - co);
    cb[idx] = cn;
    yb[idx] = yn;
    cbf[idx] = f2b(cn);
    ybf[idx] = f2b(yn);
}

extern "C" void kernel_launch(void* const* d_in, const int* in_sizes, int n_in,
                              void* d_out, int out_size, void* d_ws, size_t ws_size,
                              hipStream_t stream) {
    const float* z0 = (const float*)d_in[0];
    const float* z1 = (const float*)d_in[1];
    const float* psi = (const float*)d_in[2];
    float* out = (float*)d_out;

    char* w = (char*)d_ws;
    ushort_t* TO    = (ushort_t*)(w);                 // 16,777,216  (T, then O)
    ushort_t* psiB  = (ushort_t*)(w + 16777216);      //  4,194,304
    ushort_t* psiT  = (ushort_t*)(w + 20971520);      //  4,194,304
    float*    gpart = (float*)(w + 25165824);         //  4,194,304  (64 partials)
    float*    cbuf  = (float*)(w + 29360128);         //     65,536
    float*    ybuf  = (float*)(w + 29425664);         //     65,536
    ushort_t* cbf   = (ushort_t*)(w + 29491200);      //     32,768
    ushort_t* ybf   = (ushort_t*)(w + 29523968);      //     32,768
    // total 29,556,736 B

    // fused prologue: iter-0 outer product (2048 wgs) + psi conversion with
    // tile-transposed psiT + c/y zeroing (512 wgs).  One dispatch.
    prep0_k<<<2560, 256, 0, stream>>>(psi, psiB, psiT,
                                      (uint4*)(w + 29360128), z0, z1, TO);

    // iter 0 tail
    gemm2_k<<<256, 512, 0, stream>>>(TO, psiB, gpart);
    fista_update<<<64, 256, 0, stream>>>(gpart, cbuf, ybuf, cbf, ybf, 0);

    for (int it = 1; it < 20; ++it) {
        gemm1_k<<<1024, 256, 0, stream>>>(ybf, psiT, TO);
        krylov_k<5><<<2048, 256, 0, stream>>>(TO, z0, z1, nullptr);
        gemm2_k<<<256, 512, 0, stream>>>(TO, psiB, gpart);
        fista_update<<<64, 256, 0, stream>>>(gpart, cbuf, ybuf, cbf, ybf, it);
    }

    gemm1_k<<<1024, 256, 0, stream>>>(cbf, psiT, TO);
    krylov_k<8><<<2048, 256, 0, stream>>>(TO, z0, z1, out);
}

// Round 8
// 778.033 us; speedup vs baseline: 1.1449x; 1.0209x over previous
//
#include <hip/hip_runtime.h>
#include <hip/hip_bf16.h>

// ---------------------------------------------------------------------------
// TransportOperator: FISTA sparse coding through block-diag expm + transport.
// B=256, D=512, K=8, M=64, N=64.  20 FISTA iters, lr=0.01, lambda=0.05.
//
// R19 = R18 champion (794us) with ONE change: grad-iter Krylov order 5 -> 4.
//   ||T|| ~ 0.08 per block => NT=4 truncation ~2e-6 relative, 3 orders below
//   the bf16 resolution that already bounds the grad path; final apply stays
//   NT=8.  ~25% less krylov work (fwd/bwd levels 4->3, outer 5->4, W 25->16).
// Everything else byte-identical to R18:
//   prep0_k fused prologue (outer0 iter-0 shortcut + tile-transposed psiT),
//   gemm1 (1024 wgs), gemm2 (512thr 8-wave), fista, final gemm1+krylov<8>.
// ---------------------------------------------------------------------------

typedef __attribute__((ext_vector_type(8))) short bf16x8;
typedef __attribute__((ext_vector_type(4))) float f32x4;
typedef unsigned short ushort_t;
typedef unsigned int uint_t;

__device__ __constant__ float INVF[20] = {
    1.0f, 1.0f, 0.5f, 1.6666666666666666e-1f, 4.1666666666666664e-2f,
    8.333333333333333e-3f, 1.3888888888888889e-3f, 1.984126984126984e-4f,
    2.48015873015873e-5f, 2.7557319223985893e-6f, 2.755731922398589e-7f,
    2.505210838544172e-8f, 2.08767569878681e-9f, 1.6059043836821613e-10f,
    1.1470745597729725e-11f, 7.647163731819816e-13f, 4.779477332387385e-14f,
    2.8114572543455206e-15f, 1.5619206968586225e-16f, 8.22063524662433e-18f};

__device__ __forceinline__ ushort_t f2b(float x) {
    uint_t u = __float_as_uint(x);
    uint_t r = u + 0x7FFFu + ((u >> 16) & 1u);   // RNE
    return (ushort_t)(r >> 16);
}
__device__ __forceinline__ float b2f(ushort_t h) {
    return __uint_as_float((uint_t)h << 16);
}

// quad sum via DPP (VALU pipe, no LDS ops)
__device__ __forceinline__ float qsum4(float s) {
    int a = __builtin_amdgcn_update_dpp(0, __float_as_int(s), 0xB1, 0xF, 0xF, true);
    s += __int_as_float(a);                       // xor 1
    int b = __builtin_amdgcn_update_dpp(0, __float_as_int(s), 0x4E, 0xF, 0xF, true);
    s += __int_as_float(b);                       // xor 2
    return s;
}

// --- fused prologue: outer0 (wg<2048) + prep (wg>=2048) --------------------
// outer0: O[b,k] = (z0-z1) z0^T (T=0 => expm=I at it=0), bit-identical to
// champion gemm1+krylov<5,grad> at y=0.
// prep: psiB[e]=f2b(psi[e]) linear; psiT[k][uv][m]=f2b(psi[k][m][uv]) via
// per-wg 64x64 tile transpose (coalesced reads AND writes); zero c/y state.
__global__ __launch_bounds__(256) void prep0_k(const float* __restrict__ psi,
                                               ushort_t* __restrict__ psiB,
                                               ushort_t* __restrict__ psiT,
                                               uint4* __restrict__ zero_base,
                                               const float* __restrict__ z0,
                                               const float* __restrict__ z1,
                                               ushort_t* __restrict__ Tbf) {
    int wg = blockIdx.x;
    int tid = threadIdx.x;
    if (wg < 2048) {
        // ---- outer0 role (verbatim R16/R17 outer0_k) ----
        int bid = wg;
        int b = bid >> 3, k = bid & 7;
        int row = tid >> 2, p = tid & 3, c0 = p * 16;
        const float* zb = z0 + (size_t)b * 512 + k * 64;
        float u = zb[row] - z1[(size_t)b * 512 + k * 64 + row];
        const f32x4* vp = (const f32x4*)(zb + c0);
        f32x4 v0 = vp[0], v1 = vp[1], v2 = vp[2], v3 = vp[3];
        float o[16];
#pragma unroll
        for (int i = 0; i < 4; ++i) {
            o[i]      = u * v0[i];
            o[4 + i]  = u * v1[i];
            o[8 + i]  = u * v2[i];
            o[12 + i] = u * v3[i];
        }
        uint_t ow[8];
#pragma unroll
        for (int i = 0; i < 8; ++i)
            ow[i] = (uint_t)f2b(o[2 * i]) | ((uint_t)f2b(o[2 * i + 1]) << 16);
        uint4* op = (uint4*)(Tbf + (size_t)bid * 4096 + row * 64 + c0);
        op[0] = make_uint4(ow[0], ow[1], ow[2], ow[3]);
        op[1] = make_uint4(ow[4], ow[5], ow[6], ow[7]);
        return;
    }
    int t = wg - 2048;                 // 0..511
    if (t < 48)   // zero 48*256*16 B = 196608 B (c,y fp32 + bf16)
        zero_base[t * 256 + tid] = make_uint4(0, 0, 0, 0);
    // psiB: linear coalesced convert, 4096 elems per wg
    int base = t * 4096 + tid;
#pragma unroll
    for (int i = 0; i < 16; ++i) {
        int e = base + i * 256;                // e in [0, 2097152)
        psiB[e] = f2b(psi[e]);
    }
    // psiT: 64x64 tile transpose.  tile (k, uvb); thread (uv=tid>>2, g=tid&3)
    // gathers psi[k][g*16+i][uv0+uv] for i=0..15 (each 64B psi line consumed
    // by 16 lanes), packs, writes psiT[k][uv0+uv][g*16..+15] as 2x uint4.
    int k = t >> 6, uvb = t & 63;
    int uv = tid >> 2, g = tid & 3;
    size_t pbase = (size_t)k * 262144 + (size_t)(g * 16) * 4096 + uvb * 64 + uv;
    float v[16];
#pragma unroll
    for (int i = 0; i < 16; ++i) v[i] = psi[pbase + (size_t)i * 4096];
    uint_t ow[8];
#pragma unroll
    for (int i = 0; i < 8; ++i)
        ow[i] = (uint_t)f2b(v[2 * i]) | ((uint_t)f2b(v[2 * i + 1]) << 16);
    uint4* op = (uint4*)(psiT + (size_t)k * 262144 +
                         (size_t)(uvb * 64 + uv) * 64 + g * 16);
    op[0] = make_uint4(ow[0], ow[1], ow[2], ow[3]);
    op[1] = make_uint4(ow[4], ow[5], ow[6], ow[7]);
}

// --- GEMM1: T[b][j] = sum_m y[b,m] * psiT[j,m].  D-rows <-> j. -------------
// grid 1024 = 512 j-windows x 2 b-halves (128 b).  18 KB LDS.
__global__ __launch_bounds__(256) void gemm1_k(const ushort_t* __restrict__ ybf,
                                               const ushort_t* __restrict__ psiT,
                                               ushort_t* __restrict__ Tbf) {
    __shared__ __align__(16) ushort_t Ls[128 * 72];   // [b 128][j 64] swizzled
    int wg = blockIdx.x;
    int j0 = (wg & 511) * 64;
    int bt = wg >> 9;                   // 0..1
    int tid = threadIdx.x;
    int wave = tid >> 6, lane = tid & 63;
    int rowi = lane & 15, q = lane >> 4;
    int b0w = bt * 128 + wave * 32;

    f32x4 acc[4][2];
    const f32x4 zero = {0.f, 0.f, 0.f, 0.f};
    for (int ta = 0; ta < 4; ++ta)
        for (int tb = 0; tb < 2; ++tb) acc[ta][tb] = zero;

    for (int ks = 0; ks < 2; ++ks) {
        bf16x8 a[4], bb[2];
        for (int ta = 0; ta < 4; ++ta)
            a[ta] = *(const bf16x8*)(psiT + (size_t)(j0 + ta * 16 + rowi) * 64 +
                                     ks * 32 + q * 8);
        for (int tb = 0; tb < 2; ++tb)
            bb[tb] = *(const bf16x8*)(ybf + (size_t)(b0w + tb * 16 + rowi) * 64 +
                                      ks * 32 + q * 8);
        for (int ta = 0; ta < 4; ++ta)
            for (int tb = 0; tb < 2; ++tb)
                acc[ta][tb] = __builtin_amdgcn_mfma_f32_16x16x32_bf16(
                    a[ta], bb[tb], acc[ta][tb], 0, 0, 0);
    }
    for (int ta = 0; ta < 4; ++ta)
        for (int tb = 0; tb < 2; ++tb) {
            int bl = wave * 32 + tb * 16 + rowi;      // local b in [0,128)
            int jl = ta * 16 + q * 4;
            uint_t lo = (uint_t)f2b(acc[ta][tb][0]) | ((uint_t)f2b(acc[ta][tb][1]) << 16);
            uint_t hi = (uint_t)f2b(acc[ta][tb][2]) | ((uint_t)f2b(acc[ta][tb][3]) << 16);
            int idx = bl * 72 + ((((jl >> 3) + 2 * bl) & 7) << 3) + (jl & 7);
            *(uint2*)&Ls[idx] = make_uint2(lo, hi);
        }
    __syncthreads();
    for (int pass = 0; pass < 4; ++pass) {
        int b = pass * 32 + (tid >> 3);               // local b
        int ch = tid & 7;
        uint4 v = *(const uint4*)&Ls[b * 72 + ch * 8];
        int x = (ch - 2 * b) & 7;
        *(uint4*)(Tbf + (size_t)(bt * 128 + b) * 32768 + j0 + x * 8) = v;
    }
}

// --- Krylov: per (b,k); T in registers; grad mode writes O over T. ---------
template <int NT>
__global__ __launch_bounds__(256) void krylov_k(ushort_t* __restrict__ Tbf,
                                                const float* __restrict__ z0,
                                                const float* __restrict__ z1,
                                                float* __restrict__ out) {
    __shared__ float V[NT][64];
    __shared__ float U[NT][64];
    __shared__ float zz[64];
    int bid = blockIdx.x;
    int b = bid >> 3, k = bid & 7;
    int tid = threadIdx.x;
    int row = tid >> 2, p = tid & 3, c0 = p * 16;
    bool grad = (out == nullptr);

    const ushort_t* tbase = Tbf + (size_t)bid * 4096;
    float rowT[16];
    {
        uint4 ra = *(const uint4*)(tbase + row * 64 + c0);
        uint4 rb = *(const uint4*)(tbase + row * 64 + c0 + 8);
        uint_t wv[8] = {ra.x, ra.y, ra.z, ra.w, rb.x, rb.y, rb.z, rb.w};
        for (int i = 0; i < 8; ++i) {
            rowT[2 * i]     = __uint_as_float(wv[i] << 16);
            rowT[2 * i + 1] = __uint_as_float(wv[i] & 0xFFFF0000u);
        }
    }
    float colT[16];
    if (grad) {
#pragma unroll
        for (int i = 0; i < 16; ++i) colT[i] = b2f(tbase[(c0 + i) * 64 + row]);
    }
    if (tid < 64) {
        V[0][tid] = z0[(size_t)b * 512 + k * 64 + tid];
        zz[tid]   = z1[(size_t)b * 512 + k * 64 + tid];
    }
    __syncthreads();

    for (int l = 1; l < NT; ++l) {
        const f32x4* vp = (const f32x4*)&V[l - 1][c0];
        f32x4 v0 = vp[0], v1 = vp[1], v2 = vp[2], v3 = vp[3];
        float s0 = 0.f, s1 = 0.f, s2 = 0.f, s3 = 0.f;
#pragma unroll
        for (int i = 0; i < 4; ++i) {
            s0 = fmaf(rowT[i], v0[i], s0);
            s1 = fmaf(rowT[4 + i], v1[i], s1);
            s2 = fmaf(rowT[8 + i], v2[i], s2);
            s3 = fmaf(rowT[12 + i], v3[i], s3);
        }
        float s = qsum4((s0 + s1) + (s2 + s3));
        if (p == 0) V[l][row] = s;
        __syncthreads();
    }

    if (!grad) {
        if (tid < 64) {
            float zh = 0.f;
#pragma unroll
            for (int l = 0; l < NT; ++l) zh = fmaf(INVF[l], V[l][tid], zh);
            out[(size_t)b * 512 + k * 64 + tid] = zh;
        }
        return;
    }

    if (tid < 64) {
        float zh = 0.f;
#pragma unroll
        for (int l = 0; l < NT; ++l) zh = fmaf(INVF[l], V[l][tid], zh);
        U[0][tid] = zh - zz[tid];
    }
    __syncthreads();

    for (int j = 1; j < NT; ++j) {
        const f32x4* up = (const f32x4*)&U[j - 1][c0];
        f32x4 u0 = up[0], u1 = up[1], u2 = up[2], u3 = up[3];
        float s0 = 0.f, s1 = 0.f, s2 = 0.f, s3 = 0.f;
#pragma unroll
        for (int i = 0; i < 4; ++i) {
            s0 = fmaf(colT[i], u0[i], s0);
            s1 = fmaf(colT[4 + i], u1[i], s1);
            s2 = fmaf(colT[8 + i], u2[i], s2);
            s3 = fmaf(colT[12 + i], u3[i], s3);
        }
        float s = qsum4((s0 + s1) + (s2 + s3));
        if (p == 0) U[j][row] = s;
        __syncthreads();
    }

    float W[NT];
#pragma unroll
    for (int l = 0; l < NT; ++l) {
        float w = 0.f;
#pragma unroll
        for (int j = 0; j < NT; ++j) w = fmaf(INVF[j + l + 1], U[j][row], w);
        W[l] = w;
    }
    float o[16];
#pragma unroll
    for (int i = 0; i < 16; ++i) o[i] = 0.f;
#pragma unroll
    for (int l = 0; l < NT; ++l) {
        const f32x4* vp = (const f32x4*)&V[l][c0];
        f32x4 a0 = vp[0], a1 = vp[1], a2 = vp[2], a3 = vp[3];
        float w = W[l];
#pragma unroll
        for (int i = 0; i < 4; ++i) {
            o[i]      = fmaf(w, a0[i], o[i]);
            o[4 + i]  = fmaf(w, a1[i], o[4 + i]);
            o[8 + i]  = fmaf(w, a2[i], o[8 + i]);
            o[12 + i] = fmaf(w, a3[i], o[12 + i]);
        }
    }
    uint_t ow[8];
#pragma unroll
    for (int i = 0; i < 8; ++i)
        ow[i] = (uint_t)f2b(o[2 * i]) | ((uint_t)f2b(o[2 * i + 1]) << 16);
    uint4* op = (uint4*)(Tbf + (size_t)bid * 4096 + row * 64 + c0);
    op[0] = make_uint4(ow[0], ow[1], ow[2], ow[3]);
    op[1] = make_uint4(ow[4], ow[5], ow[6], ow[7]);
}

// --- GEMM2: gpart[kc][b][m] = sum_{uv in chunk} O[b][.] psiB[m][.] ---------
// grid 256 = 4 bt x 64 kc (champion tiling/traffic); block 512 = 8 waves,
// each wave takes a 64-uv slice (2 ks) -> 8 waves/CU latency hiding (was 4).
// 8 private LDS partials (139.3 KB, 1 wg/CU), ONE barrier, pairwise reduce.
__global__ __launch_bounds__(512) void gemm2_k(const ushort_t* __restrict__ Obf,
                                               const ushort_t* __restrict__ psiB,
                                               float* __restrict__ gpart) {
    __shared__ __align__(16) float Lg[8][64 * 68];    // [w][b 64][m 64] str 68
    int bt = blockIdx.x & 3;
    int kc = blockIdx.x >> 2;          // 0..63
    int k = kc >> 3;
    int uv0 = (kc & 7) * 512;
    int tid = threadIdx.x, wave = tid >> 6, lane = tid & 63;
    int rowi = lane & 15, q = lane >> 4;

    f32x4 acc[4][4];
    const f32x4 zero = {0.f, 0.f, 0.f, 0.f};
    for (int ta = 0; ta < 4; ++ta)
        for (int tb = 0; tb < 4; ++tb) acc[ta][tb] = zero;

    for (int ks = 0; ks < 2; ++ks) {
        int off = uv0 + wave * 64 + ks * 32 + q * 8;
        bf16x8 a[4], bb[4];
        for (int ta = 0; ta < 4; ++ta)
            a[ta] = *(const bf16x8*)(psiB + (size_t)k * 262144 +
                                     (size_t)(ta * 16 + rowi) * 4096 + off);
        for (int tb = 0; tb < 4; ++tb)
            bb[tb] = *(const bf16x8*)(Obf +
                                      (size_t)(bt * 64 + tb * 16 + rowi) * 32768 +
                                      k * 4096 + off);
        for (int ta = 0; ta < 4; ++ta)
            for (int tb = 0; tb < 4; ++tb)
                acc[ta][tb] = __builtin_amdgcn_mfma_f32_16x16x32_bf16(
                    a[ta], bb[tb], acc[ta][tb], 0, 0, 0);
    }
    float* lw = &Lg[wave][0];
    for (int ta = 0; ta < 4; ++ta)
        for (int tb = 0; tb < 4; ++tb)
            *(f32x4*)&lw[(tb * 16 + rowi) * 68 + ta * 16 + q * 4] = acc[ta][tb];
    __syncthreads();

    int b = tid >> 3, m0 = (tid & 7) * 8;            // 64 b x 8 m per thread
    const float* l0 = &Lg[0][b * 68 + m0];
    float* gp = gpart + (size_t)kc * 16384 + (size_t)(bt * 64 + b) * 64 + m0;
#pragma unroll
    for (int i = 0; i < 2; ++i) {
        f32x4 s0 = *(const f32x4*)(l0 + 0 * 4352 + 4 * i);
        f32x4 s1 = *(const f32x4*)(l0 + 1 * 4352 + 4 * i);
        f32x4 s2 = *(const f32x4*)(l0 + 2 * 4352 + 4 * i);
        f32x4 s3 = *(const f32x4*)(l0 + 3 * 4352 + 4 * i);
        f32x4 s4 = *(const f32x4*)(l0 + 4 * 4352 + 4 * i);
        f32x4 s5 = *(const f32x4*)(l0 + 5 * 4352 + 4 * i);
        f32x4 s6 = *(const f32x4*)(l0 + 6 * 4352 + 4 * i);
        f32x4 s7 = *(const f32x4*)(l0 + 7 * 4352 + 4 * i);
        f32x4 s = ((s0 + s1) + (s2 + s3)) + ((s4 + s5) + (s6 + s7));
        *(f32x4*)(gp + 4 * i) = s;
    }
}

// --- FISTA: reduce 64 partials + prox step; maintain fp32 + bf16 state -----
__global__ __launch_bounds__(256) void fista_update(const float* __restrict__ gpart,
                                                    float* __restrict__ cb,
                                                    float* __restrict__ yb,
                                                    ushort_t* __restrict__ cbf,
                                                    ushort_t* __restrict__ ybf,
                                                    int iter) {
    int idx = blockIdx.x * 256 + threadIdx.x;
    float a0 = 0.f, a1 = 0.f, a2 = 0.f, a3 = 0.f;
#pragma unroll
    for (int p = 0; p < 64; p += 4) {
        a0 += gpart[(size_t)p * 16384 + idx];
        a1 += gpart[(size_t)(p + 1) * 16384 + idx];
        a2 += gpart[(size_t)(p + 2) * 16384 + idx];
        a3 += gpart[(size_t)(p + 3) * 16384 + idx];
    }
    float gv = (a0 + a1) + (a2 + a3);
    float t = 1.f;
    for (int s = 0; s < iter; ++s) t = 0.5f * (1.f + sqrtf(1.f + 4.f * t * t));
    float tn = 0.5f * (1.f + sqrtf(1.f + 4.f * t * t));
    float beta = (t - 1.f) / tn;
    float co = cb[idx], yo = yb[idx];
    float a = yo - 0.01f * gv;
    float thr = 0.01f * 0.05f;
    float cn = copysignf(fmaxf(fabsf(a) - thr, 0.f), a);
    float yn = cn + beta * (cn - co);
    cb[idx] = cn;
    yb[idx] = yn;
    cbf[idx] = f2b(cn);
    ybf[idx] = f2b(yn);
}

extern "C" void kernel_launch(void* const* d_in, const int* in_sizes, int n_in,
                              void* d_out, int out_size, void* d_ws, size_t ws_size,
                              hipStream_t stream) {
    const float* z0 = (const float*)d_in[0];
    const float* z1 = (const float*)d_in[1];
    const float* psi = (const float*)d_in[2];
    float* out = (float*)d_out;

    char* w = (char*)d_ws;
    ushort_t* TO    = (ushort_t*)(w);                 // 16,777,216  (T, then O)
    ushort_t* psiB  = (ushort_t*)(w + 16777216);      //  4,194,304
    ushort_t* psiT  = (ushort_t*)(w + 20971520);      //  4,194,304
    float*    gpart = (float*)(w + 25165824);         //  4,194,304  (64 partials)
    float*    cbuf  = (float*)(w + 29360128);         //     65,536
    float*    ybuf  = (float*)(w + 29425664);         //     65,536
    ushort_t* cbf   = (ushort_t*)(w + 29491200);      //     32,768
    ushort_t* ybf   = (ushort_t*)(w + 29523968);      //     32,768
    // total 29,556,736 B

    // fused prologue: iter-0 outer product (2048 wgs) + psi conversion with
    // tile-transposed psiT + c/y zeroing (512 wgs).  One dispatch.
    prep0_k<<<2560, 256, 0, stream>>>(psi, psiB, psiT,
                                      (uint4*)(w + 29360128), z0, z1, TO);

    // iter 0 tail
    gemm2_k<<<256, 512, 0, stream>>>(TO, psiB, gpart);
    fista_update<<<64, 256, 0, stream>>>(gpart, cbuf, ybuf, cbf, ybf, 0);

    for (int it = 1; it < 20; ++it) {
        gemm1_k<<<1024, 256, 0, stream>>>(ybf, psiT, TO);
        krylov_k<4><<<2048, 256, 0, stream>>>(TO, z0, z1, nullptr);
        gemm2_k<<<256, 512, 0, stream>>>(TO, psiB, gpart);
        fista_update<<<64, 256, 0, stream>>>(gpart, cbuf, ybuf, cbf, ybf, it);
    }

    gemm1_k<<<1024, 256, 0, stream>>>(cbf, psiT, TO);
    krylov_k<8><<<2048, 256, 0, stream>>>(TO, z0, z1, out);
}

// Round 9
// 771.905 us; speedup vs baseline: 1.1540x; 1.0079x over previous
//
#include <hip/hip_runtime.h>
#include <hip/hip_bf16.h>

// ---------------------------------------------------------------------------
// TransportOperator: FISTA sparse coding through block-diag expm + transport.
// B=256, D=512, K=8, M=64, N=64.  20 FISTA iters, lr=0.01, lambda=0.05.
//
// R20 = R19 champion (778us) with the Taylor-order lever pushed to its floor:
//   grad-iter Krylov NT 4 -> 3   (truncation ~8.5e-5, 50x below the bf16-T
//     quantization the pipeline already carries; Frechet terms to order 4).
//   final-apply Krylov NT 8 -> 6 (truncation ~4e-10, unconditionally safe).
// Everything else byte-identical to R19:
//   prep0_k fused prologue (outer0 iter-0 shortcut + tile-transposed psiT),
//   gemm1 (1024 wgs), gemm2 (512thr 8-wave), fista.
// ---------------------------------------------------------------------------

typedef __attribute__((ext_vector_type(8))) short bf16x8;
typedef __attribute__((ext_vector_type(4))) float f32x4;
typedef unsigned short ushort_t;
typedef unsigned int uint_t;

__device__ __constant__ float INVF[20] = {
    1.0f, 1.0f, 0.5f, 1.6666666666666666e-1f, 4.1666666666666664e-2f,
    8.333333333333333e-3f, 1.3888888888888889e-3f, 1.984126984126984e-4f,
    2.48015873015873e-5f, 2.7557319223985893e-6f, 2.755731922398589e-7f,
    2.505210838544172e-8f, 2.08767569878681e-9f, 1.6059043836821613e-10f,
    1.1470745597729725e-11f, 7.647163731819816e-13f, 4.779477332387385e-14f,
    2.8114572543455206e-15f, 1.5619206968586225e-16f, 8.22063524662433e-18f};

__device__ __forceinline__ ushort_t f2b(float x) {
    uint_t u = __float_as_uint(x);
    uint_t r = u + 0x7FFFu + ((u >> 16) & 1u);   // RNE
    return (ushort_t)(r >> 16);
}
__device__ __forceinline__ float b2f(ushort_t h) {
    return __uint_as_float((uint_t)h << 16);
}

// quad sum via DPP (VALU pipe, no LDS ops)
__device__ __forceinline__ float qsum4(float s) {
    int a = __builtin_amdgcn_update_dpp(0, __float_as_int(s), 0xB1, 0xF, 0xF, true);
    s += __int_as_float(a);                       // xor 1
    int b = __builtin_amdgcn_update_dpp(0, __float_as_int(s), 0x4E, 0xF, 0xF, true);
    s += __int_as_float(b);                       // xor 2
    return s;
}

// --- fused prologue: outer0 (wg<2048) + prep (wg>=2048) --------------------
// outer0: O[b,k] = (z0-z1) z0^T (T=0 => expm=I at it=0), bit-identical to
// champion gemm1+krylov<grad> at y=0.
// prep: psiB[e]=f2b(psi[e]) linear; psiT[k][uv][m]=f2b(psi[k][m][uv]) via
// per-wg 64x64 tile transpose (coalesced reads AND writes); zero c/y state.
__global__ __launch_bounds__(256) void prep0_k(const float* __restrict__ psi,
                                               ushort_t* __restrict__ psiB,
                                               ushort_t* __restrict__ psiT,
                                               uint4* __restrict__ zero_base,
                                               const float* __restrict__ z0,
                                               const float* __restrict__ z1,
                                               ushort_t* __restrict__ Tbf) {
    int wg = blockIdx.x;
    int tid = threadIdx.x;
    if (wg < 2048) {
        // ---- outer0 role (verbatim R16/R17 outer0_k) ----
        int bid = wg;
        int b = bid >> 3, k = bid & 7;
        int row = tid >> 2, p = tid & 3, c0 = p * 16;
        const float* zb = z0 + (size_t)b * 512 + k * 64;
        float u = zb[row] - z1[(size_t)b * 512 + k * 64 + row];
        const f32x4* vp = (const f32x4*)(zb + c0);
        f32x4 v0 = vp[0], v1 = vp[1], v2 = vp[2], v3 = vp[3];
        float o[16];
#pragma unroll
        for (int i = 0; i < 4; ++i) {
            o[i]      = u * v0[i];
            o[4 + i]  = u * v1[i];
            o[8 + i]  = u * v2[i];
            o[12 + i] = u * v3[i];
        }
        uint_t ow[8];
#pragma unroll
        for (int i = 0; i < 8; ++i)
            ow[i] = (uint_t)f2b(o[2 * i]) | ((uint_t)f2b(o[2 * i + 1]) << 16);
        uint4* op = (uint4*)(Tbf + (size_t)bid * 4096 + row * 64 + c0);
        op[0] = make_uint4(ow[0], ow[1], ow[2], ow[3]);
        op[1] = make_uint4(ow[4], ow[5], ow[6], ow[7]);
        return;
    }
    int t = wg - 2048;                 // 0..511
    if (t < 48)   // zero 48*256*16 B = 196608 B (c,y fp32 + bf16)
        zero_base[t * 256 + tid] = make_uint4(0, 0, 0, 0);
    // psiB: linear coalesced convert, 4096 elems per wg
    int base = t * 4096 + tid;
#pragma unroll
    for (int i = 0; i < 16; ++i) {
        int e = base + i * 256;                // e in [0, 2097152)
        psiB[e] = f2b(psi[e]);
    }
    // psiT: 64x64 tile transpose.  tile (k, uvb); thread (uv=tid>>2, g=tid&3)
    // gathers psi[k][g*16+i][uv0+uv] for i=0..15 (each 64B psi line consumed
    // by 16 lanes), packs, writes psiT[k][uv0+uv][g*16..+15] as 2x uint4.
    int k = t >> 6, uvb = t & 63;
    int uv = tid >> 2, g = tid & 3;
    size_t pbase = (size_t)k * 262144 + (size_t)(g * 16) * 4096 + uvb * 64 + uv;
    float v[16];
#pragma unroll
    for (int i = 0; i < 16; ++i) v[i] = psi[pbase + (size_t)i * 4096];
    uint_t ow[8];
#pragma unroll
    for (int i = 0; i < 8; ++i)
        ow[i] = (uint_t)f2b(v[2 * i]) | ((uint_t)f2b(v[2 * i + 1]) << 16);
    uint4* op = (uint4*)(psiT + (size_t)k * 262144 +
                         (size_t)(uvb * 64 + uv) * 64 + g * 16);
    op[0] = make_uint4(ow[0], ow[1], ow[2], ow[3]);
    op[1] = make_uint4(ow[4], ow[5], ow[6], ow[7]);
}

// --- GEMM1: T[b][j] = sum_m y[b,m] * psiT[j,m].  D-rows <-> j. -------------
// grid 1024 = 512 j-windows x 2 b-halves (128 b).  18 KB LDS.
__global__ __launch_bounds__(256) void gemm1_k(const ushort_t* __restrict__ ybf,
                                               const ushort_t* __restrict__ psiT,
                                               ushort_t* __restrict__ Tbf) {
    __shared__ __align__(16) ushort_t Ls[128 * 72];   // [b 128][j 64] swizzled
    int wg = blockIdx.x;
    int j0 = (wg & 511) * 64;
    int bt = wg >> 9;                   // 0..1
    int tid = threadIdx.x;
    int wave = tid >> 6, lane = tid & 63;
    int rowi = lane & 15, q = lane >> 4;
    int b0w = bt * 128 + wave * 32;

    f32x4 acc[4][2];
    const f32x4 zero = {0.f, 0.f, 0.f, 0.f};
    for (int ta = 0; ta < 4; ++ta)
        for (int tb = 0; tb < 2; ++tb) acc[ta][tb] = zero;

    for (int ks = 0; ks < 2; ++ks) {
        bf16x8 a[4], bb[2];
        for (int ta = 0; ta < 4; ++ta)
            a[ta] = *(const bf16x8*)(psiT + (size_t)(j0 + ta * 16 + rowi) * 64 +
                                     ks * 32 + q * 8);
        for (int tb = 0; tb < 2; ++tb)
            bb[tb] = *(const bf16x8*)(ybf + (size_t)(b0w + tb * 16 + rowi) * 64 +
                                      ks * 32 + q * 8);
        for (int ta = 0; ta < 4; ++ta)
            for (int tb = 0; tb < 2; ++tb)
                acc[ta][tb] = __builtin_amdgcn_mfma_f32_16x16x32_bf16(
                    a[ta], bb[tb], acc[ta][tb], 0, 0, 0);
    }
    for (int ta = 0; ta < 4; ++ta)
        for (int tb = 0; tb < 2; ++tb) {
            int bl = wave * 32 + tb * 16 + rowi;      // local b in [0,128)
            int jl = ta * 16 + q * 4;
            uint_t lo = (uint_t)f2b(acc[ta][tb][0]) | ((uint_t)f2b(acc[ta][tb][1]) << 16);
            uint_t hi = (uint_t)f2b(acc[ta][tb][2]) | ((uint_t)f2b(acc[ta][tb][3]) << 16);
            int idx = bl * 72 + ((((jl >> 3) + 2 * bl) & 7) << 3) + (jl & 7);
            *(uint2*)&Ls[idx] = make_uint2(lo, hi);
        }
    __syncthreads();
    for (int pass = 0; pass < 4; ++pass) {
        int b = pass * 32 + (tid >> 3);               // local b
        int ch = tid & 7;
        uint4 v = *(const uint4*)&Ls[b * 72 + ch * 8];
        int x = (ch - 2 * b) & 7;
        *(uint4*)(Tbf + (size_t)(bt * 128 + b) * 32768 + j0 + x * 8) = v;
    }
}

// --- Krylov: per (b,k); T in registers; grad mode writes O over T. ---------
template <int NT>
__global__ __launch_bounds__(256) void krylov_k(ushort_t* __restrict__ Tbf,
                                                const float* __restrict__ z0,
                                                const float* __restrict__ z1,
                                                float* __restrict__ out) {
    __shared__ float V[NT][64];
    __shared__ float U[NT][64];
    __shared__ float zz[64];
    int bid = blockIdx.x;
    int b = bid >> 3, k = bid & 7;
    int tid = threadIdx.x;
    int row = tid >> 2, p = tid & 3, c0 = p * 16;
    bool grad = (out == nullptr);

    const ushort_t* tbase = Tbf + (size_t)bid * 4096;
    float rowT[16];
    {
        uint4 ra = *(const uint4*)(tbase + row * 64 + c0);
        uint4 rb = *(const uint4*)(tbase + row * 64 + c0 + 8);
        uint_t wv[8] = {ra.x, ra.y, ra.z, ra.w, rb.x, rb.y, rb.z, rb.w};
        for (int i = 0; i < 8; ++i) {
            rowT[2 * i]     = __uint_as_float(wv[i] << 16);
            rowT[2 * i + 1] = __uint_as_float(wv[i] & 0xFFFF0000u);
        }
    }
    float colT[16];
    if (grad) {
#pragma unroll
        for (int i = 0; i < 16; ++i) colT[i] = b2f(tbase[(c0 + i) * 64 + row]);
    }
    if (tid < 64) {
        V[0][tid] = z0[(size_t)b * 512 + k * 64 + tid];
        zz[tid]   = z1[(size_t)b * 512 + k * 64 + tid];
    }
    __syncthreads();

    for (int l = 1; l < NT; ++l) {
        const f32x4* vp = (const f32x4*)&V[l - 1][c0];
        f32x4 v0 = vp[0], v1 = vp[1], v2 = vp[2], v3 = vp[3];
        float s0 = 0.f, s1 = 0.f, s2 = 0.f, s3 = 0.f;
#pragma unroll
        for (int i = 0; i < 4; ++i) {
            s0 = fmaf(rowT[i], v0[i], s0);
            s1 = fmaf(rowT[4 + i], v1[i], s1);
            s2 = fmaf(rowT[8 + i], v2[i], s2);
            s3 = fmaf(rowT[12 + i], v3[i], s3);
        }
        float s = qsum4((s0 + s1) + (s2 + s3));
        if (p == 0) V[l][row] = s;
        __syncthreads();
    }

    if (!grad) {
        if (tid < 64) {
            float zh = 0.f;
#pragma unroll
            for (int l = 0; l < NT; ++l) zh = fmaf(INVF[l], V[l][tid], zh);
            out[(size_t)b * 512 + k * 64 + tid] = zh;
        }
        return;
    }

    if (tid < 64) {
        float zh = 0.f;
#pragma unroll
        for (int l = 0; l < NT; ++l) zh = fmaf(INVF[l], V[l][tid], zh);
        U[0][tid] = zh - zz[tid];
    }
    __syncthreads();

    for (int j = 1; j < NT; ++j) {
        const f32x4* up = (const f32x4*)&U[j - 1][c0];
        f32x4 u0 = up[0], u1 = up[1], u2 = up[2], u3 = up[3];
        float s0 = 0.f, s1 = 0.f, s2 = 0.f, s3 = 0.f;
#pragma unroll
        for (int i = 0; i < 4; ++i) {
            s0 = fmaf(colT[i], u0[i], s0);
            s1 = fmaf(colT[4 + i], u1[i], s1);
            s2 = fmaf(colT[8 + i], u2[i], s2);
            s3 = fmaf(colT[12 + i], u3[i], s3);
        }
        float s = qsum4((s0 + s1) + (s2 + s3));
        if (p == 0) U[j][row] = s;
        __syncthreads();
    }

    float W[NT];
#pragma unroll
    for (int l = 0; l < NT; ++l) {
        float w = 0.f;
#pragma unroll
        for (int j = 0; j < NT; ++j) w = fmaf(INVF[j + l + 1], U[j][row], w);
        W[l] = w;
    }
    float o[16];
#pragma unroll
    for (int i = 0; i < 16; ++i) o[i] = 0.f;
#pragma unroll
    for (int l = 0; l < NT; ++l) {
        const f32x4* vp = (const f32x4*)&V[l][c0];
        f32x4 a0 = vp[0], a1 = vp[1], a2 = vp[2], a3 = vp[3];
        float w = W[l];
#pragma unroll
        for (int i = 0; i < 4; ++i) {
            o[i]      = fmaf(w, a0[i], o[i]);
            o[4 + i]  = fmaf(w, a1[i], o[4 + i]);
            o[8 + i]  = fmaf(w, a2[i], o[8 + i]);
            o[12 + i] = fmaf(w, a3[i], o[12 + i]);
        }
    }
    uint_t ow[8];
#pragma unroll
    for (int i = 0; i < 8; ++i)
        ow[i] = (uint_t)f2b(o[2 * i]) | ((uint_t)f2b(o[2 * i + 1]) << 16);
    uint4* op = (uint4*)(Tbf + (size_t)bid * 4096 + row * 64 + c0);
    op[0] = make_uint4(ow[0], ow[1], ow[2], ow[3]);
    op[1] = make_uint4(ow[4], ow[5], ow[6], ow[7]);
}

// --- GEMM2: gpart[kc][b][m] = sum_{uv in chunk} O[b][.] psiB[m][.] ---------
// grid 256 = 4 bt x 64 kc (champion tiling/traffic); block 512 = 8 waves,
// each wave takes a 64-uv slice (2 ks) -> 8 waves/CU latency hiding (was 4).
// 8 private LDS partials (139.3 KB, 1 wg/CU), ONE barrier, pairwise reduce.
__global__ __launch_bounds__(512) void gemm2_k(const ushort_t* __restrict__ Obf,
                                               const ushort_t* __restrict__ psiB,
                                               float* __restrict__ gpart) {
    __shared__ __align__(16) float Lg[8][64 * 68];    // [w][b 64][m 64] str 68
    int bt = blockIdx.x & 3;
    int kc = blockIdx.x >> 2;          // 0..63
    int k = kc >> 3;
    int uv0 = (kc & 7) * 512;
    int tid = threadIdx.x, wave = tid >> 6, lane = tid & 63;
    int rowi = lane & 15, q = lane >> 4;

    f32x4 acc[4][4];
    const f32x4 zero = {0.f, 0.f, 0.f, 0.f};
    for (int ta = 0; ta < 4; ++ta)
        for (int tb = 0; tb < 4; ++tb) acc[ta][tb] = zero;

    for (int ks = 0; ks < 2; ++ks) {
        int off = uv0 + wave * 64 + ks * 32 + q * 8;
        bf16x8 a[4], bb[4];
        for (int ta = 0; ta < 4; ++ta)
            a[ta] = *(const bf16x8*)(psiB + (size_t)k * 262144 +
                                     (size_t)(ta * 16 + rowi) * 4096 + off);
        for (int tb = 0; tb < 4; ++tb)
            bb[tb] = *(const bf16x8*)(Obf +
                                      (size_t)(bt * 64 + tb * 16 + rowi) * 32768 +
                                      k * 4096 + off);
        for (int ta = 0; ta < 4; ++ta)
            for (int tb = 0; tb < 4; ++tb)
                acc[ta][tb] = __builtin_amdgcn_mfma_f32_16x16x32_bf16(
                    a[ta], bb[tb], acc[ta][tb], 0, 0, 0);
    }
    float* lw = &Lg[wave][0];
    for (int ta = 0; ta < 4; ++ta)
        for (int tb = 0; tb < 4; ++tb)
            *(f32x4*)&lw[(tb * 16 + rowi) * 68 + ta * 16 + q * 4] = acc[ta][tb];
    __syncthreads();

    int b = tid >> 3, m0 = (tid & 7) * 8;            // 64 b x 8 m per thread
    const float* l0 = &Lg[0][b * 68 + m0];
    float* gp = gpart + (size_t)kc * 16384 + (size_t)(bt * 64 + b) * 64 + m0;
#pragma unroll
    for (int i = 0; i < 2; ++i) {
        f32x4 s0 = *(const f32x4*)(l0 + 0 * 4352 + 4 * i);
        f32x4 s1 = *(const f32x4*)(l0 + 1 * 4352 + 4 * i);
        f32x4 s2 = *(const f32x4*)(l0 + 2 * 4352 + 4 * i);
        f32x4 s3 = *(const f32x4*)(l0 + 3 * 4352 + 4 * i);
        f32x4 s4 = *(const f32x4*)(l0 + 4 * 4352 + 4 * i);
        f32x4 s5 = *(const f32x4*)(l0 + 5 * 4352 + 4 * i);
        f32x4 s6 = *(const f32x4*)(l0 + 6 * 4352 + 4 * i);
        f32x4 s7 = *(const f32x4*)(l0 + 7 * 4352 + 4 * i);
        f32x4 s = ((s0 + s1) + (s2 + s3)) + ((s4 + s5) + (s6 + s7));
        *(f32x4*)(gp + 4 * i) = s;
    }
}

// --- FISTA: reduce 64 partials + prox step; maintain fp32 + bf16 state -----
__global__ __launch_bounds__(256) void fista_update(const float* __restrict__ gpart,
                                                    float* __restrict__ cb,
                                                    float* __restrict__ yb,
                                                    ushort_t* __restrict__ cbf,
                                                    ushort_t* __restrict__ ybf,
                                                    int iter) {
    int idx = blockIdx.x * 256 + threadIdx.x;
    float a0 = 0.f, a1 = 0.f, a2 = 0.f, a3 = 0.f;
#pragma unroll
    for (int p = 0; p < 64; p += 4) {
        a0 += gpart[(size_t)p * 16384 + idx];
        a1 += gpart[(size_t)(p + 1) * 16384 + idx];
        a2 += gpart[(size_t)(p + 2) * 16384 + idx];
        a3 += gpart[(size_t)(p + 3) * 16384 + idx];
    }
    float gv = (a0 + a1) + (a2 + a3);
    float t = 1.f;
    for (int s = 0; s < iter; ++s) t = 0.5f * (1.f + sqrtf(1.f + 4.f * t * t));
    float tn = 0.5f * (1.f + sqrtf(1.f + 4.f * t * t));
    float beta = (t - 1.f) / tn;
    float co = cb[idx], yo = yb[idx];
    float a = yo - 0.01f * gv;
    float thr = 0.01f * 0.05f;
    float cn = copysignf(fmaxf(fabsf(a) - thr, 0.f), a);
    float yn = cn + beta * (cn - co);
    cb[idx] = cn;
    yb[idx] = yn;
    cbf[idx] = f2b(cn);
    ybf[idx] = f2b(yn);
}

extern "C" void kernel_launch(void* const* d_in, const int* in_sizes, int n_in,
                              void* d_out, int out_size, void* d_ws, size_t ws_size,
                              hipStream_t stream) {
    const float* z0 = (const float*)d_in[0];
    const float* z1 = (const float*)d_in[1];
    const float* psi = (const float*)d_in[2];
    float* out = (float*)d_out;

    char* w = (char*)d_ws;
    ushort_t* TO    = (ushort_t*)(w);                 // 16,777,216  (T, then O)
    ushort_t* psiB  = (ushort_t*)(w + 16777216);      //  4,194,304
    ushort_t* psiT  = (ushort_t*)(w + 20971520);      //  4,194,304
    float*    gpart = (float*)(w + 25165824);         //  4,194,304  (64 partials)
    float*    cbuf  = (float*)(w + 29360128);         //     65,536
    float*    ybuf  = (float*)(w + 29425664);         //     65,536
    ushort_t* cbf   = (ushort_t*)(w + 29491200);      //     32,768
    ushort_t* ybf   = (ushort_t*)(w + 29523968);      //     32,768
    // total 29,556,736 B

    // fused prologue: iter-0 outer product (2048 wgs) + psi conversion with
    // tile-transposed psiT + c/y zeroing (512 wgs).  One dispatch.
    prep0_k<<<2560, 256, 0, stream>>>(psi, psiB, psiT,
                                      (uint4*)(w + 29360128), z0, z1, TO);

    // iter 0 tail
    gemm2_k<<<256, 512, 0, stream>>>(TO, psiB, gpart);
    fista_update<<<64, 256, 0, stream>>>(gpart, cbuf, ybuf, cbf, ybf, 0);

    for (int it = 1; it < 20; ++it) {
        gemm1_k<<<1024, 256, 0, stream>>>(ybf, psiT, TO);
        krylov_k<3><<<2048, 256, 0, stream>>>(TO, z0, z1, nullptr);
        gemm2_k<<<256, 512, 0, stream>>>(TO, psiB, gpart);
        fista_update<<<64, 256, 0, stream>>>(gpart, cbuf, ybuf, cbf, ybf, it);
    }

    gemm1_k<<<1024, 256, 0, stream>>>(cbf, psiT, TO);
    krylov_k<6><<<2048, 256, 0, stream>>>(TO, z0, z1, out);
}

// Round 10
// 767.891 us; speedup vs baseline: 1.1600x; 1.0052x over previous
//
#include <hip/hip_runtime.h>
#include <hip/hip_bf16.h>

// ---------------------------------------------------------------------------
// TransportOperator: FISTA sparse coding through block-diag expm + transport.
// B=256, D=512, K=8, M=64, N=64.  20 FISTA iters, lr=0.01, lambda=0.05.
//
// R21 = R20 champion (772us) with ONE isolated change: fista_update spread
// from 64 wgs (25% CU coverage, 64 serial stride-64KB loads/thread,
// latency-bound) to 256 wgs x 256 thr: thread (pg,e) sums 16 partials
// (4 chains of 4), LDS 4-way reduce, 64 threads prox+write.  Identical
// gpart traffic, 4x CU coverage, 4x shorter chains -- same mechanism as
// R17's gemm2 occupancy win.
// Everything else byte-identical to R20: prep0_k fused prologue, gemm1,
// krylov<3> grad / <6> final apply, gemm2 (512thr 8-wave).
// ---------------------------------------------------------------------------

typedef __attribute__((ext_vector_type(8))) short bf16x8;
typedef __attribute__((ext_vector_type(4))) float f32x4;
typedef unsigned short ushort_t;
typedef unsigned int uint_t;

__device__ __constant__ float INVF[20] = {
    1.0f, 1.0f, 0.5f, 1.6666666666666666e-1f, 4.1666666666666664e-2f,
    8.333333333333333e-3f, 1.3888888888888889e-3f, 1.984126984126984e-4f,
    2.48015873015873e-5f, 2.7557319223985893e-6f, 2.755731922398589e-7f,
    2.505210838544172e-8f, 2.08767569878681e-9f, 1.6059043836821613e-10f,
    1.1470745597729725e-11f, 7.647163731819816e-13f, 4.779477332387385e-14f,
    2.8114572543455206e-15f, 1.5619206968586225e-16f, 8.22063524662433e-18f};

__device__ __forceinline__ ushort_t f2b(float x) {
    uint_t u = __float_as_uint(x);
    uint_t r = u + 0x7FFFu + ((u >> 16) & 1u);   // RNE
    return (ushort_t)(r >> 16);
}
__device__ __forceinline__ float b2f(ushort_t h) {
    return __uint_as_float((uint_t)h << 16);
}

// quad sum via DPP (VALU pipe, no LDS ops)
__device__ __forceinline__ float qsum4(float s) {
    int a = __builtin_amdgcn_update_dpp(0, __float_as_int(s), 0xB1, 0xF, 0xF, true);
    s += __int_as_float(a);                       // xor 1
    int b = __builtin_amdgcn_update_dpp(0, __float_as_int(s), 0x4E, 0xF, 0xF, true);
    s += __int_as_float(b);                       // xor 2
    return s;
}

// --- fused prologue: outer0 (wg<2048) + prep (wg>=2048) --------------------
// outer0: O[b,k] = (z0-z1) z0^T (T=0 => expm=I at it=0), bit-identical to
// champion gemm1+krylov<grad> at y=0.
// prep: psiB[e]=f2b(psi[e]) linear; psiT[k][uv][m]=f2b(psi[k][m][uv]) via
// per-wg 64x64 tile transpose (coalesced reads AND writes); zero c/y state.
__global__ __launch_bounds__(256) void prep0_k(const float* __restrict__ psi,
                                               ushort_t* __restrict__ psiB,
                                               ushort_t* __restrict__ psiT,
                                               uint4* __restrict__ zero_base,
                                               const float* __restrict__ z0,
                                               const float* __restrict__ z1,
                                               ushort_t* __restrict__ Tbf) {
    int wg = blockIdx.x;
    int tid = threadIdx.x;
    if (wg < 2048) {
        // ---- outer0 role (verbatim R16/R17 outer0_k) ----
        int bid = wg;
        int b = bid >> 3, k = bid & 7;
        int row = tid >> 2, p = tid & 3, c0 = p * 16;
        const float* zb = z0 + (size_t)b * 512 + k * 64;
        float u = zb[row] - z1[(size_t)b * 512 + k * 64 + row];
        const f32x4* vp = (const f32x4*)(zb + c0);
        f32x4 v0 = vp[0], v1 = vp[1], v2 = vp[2], v3 = vp[3];
        float o[16];
#pragma unroll
        for (int i = 0; i < 4; ++i) {
            o[i]      = u * v0[i];
            o[4 + i]  = u * v1[i];
            o[8 + i]  = u * v2[i];
            o[12 + i] = u * v3[i];
        }
        uint_t ow[8];
#pragma unroll
        for (int i = 0; i < 8; ++i)
            ow[i] = (uint_t)f2b(o[2 * i]) | ((uint_t)f2b(o[2 * i + 1]) << 16);
        uint4* op = (uint4*)(Tbf + (size_t)bid * 4096 + row * 64 + c0);
        op[0] = make_uint4(ow[0], ow[1], ow[2], ow[3]);
        op[1] = make_uint4(ow[4], ow[5], ow[6], ow[7]);
        return;
    }
    int t = wg - 2048;                 // 0..511
    if (t < 48)   // zero 48*256*16 B = 196608 B (c,y fp32 + bf16)
        zero_base[t * 256 + tid] = make_uint4(0, 0, 0, 0);
    // psiB: linear coalesced convert, 4096 elems per wg
    int base = t * 4096 + tid;
#pragma unroll
    for (int i = 0; i < 16; ++i) {
        int e = base + i * 256;                // e in [0, 2097152)
        psiB[e] = f2b(psi[e]);
    }
    // psiT: 64x64 tile transpose.  tile (k, uvb); thread (uv=tid>>2, g=tid&3)
    // gathers psi[k][g*16+i][uv0+uv] for i=0..15 (each 64B psi line consumed
    // by 16 lanes), packs, writes psiT[k][uv0+uv][g*16..+15] as 2x uint4.
    int k = t >> 6, uvb = t & 63;
    int uv = tid >> 2, g = tid & 3;
    size_t pbase = (size_t)k * 262144 + (size_t)(g * 16) * 4096 + uvb * 64 + uv;
    float v[16];
#pragma unroll
    for (int i = 0; i < 16; ++i) v[i] = psi[pbase + (size_t)i * 4096];
    uint_t ow[8];
#pragma unroll
    for (int i = 0; i < 8; ++i)
        ow[i] = (uint_t)f2b(v[2 * i]) | ((uint_t)f2b(v[2 * i + 1]) << 16);
    uint4* op = (uint4*)(psiT + (size_t)k * 262144 +
                         (size_t)(uvb * 64 + uv) * 64 + g * 16);
    op[0] = make_uint4(ow[0], ow[1], ow[2], ow[3]);
    op[1] = make_uint4(ow[4], ow[5], ow[6], ow[7]);
}

// --- GEMM1: T[b][j] = sum_m y[b,m] * psiT[j,m].  D-rows <-> j. -------------
// grid 1024 = 512 j-windows x 2 b-halves (128 b).  18 KB LDS.
__global__ __launch_bounds__(256) void gemm1_k(const ushort_t* __restrict__ ybf,
                                               const ushort_t* __restrict__ psiT,
                                               ushort_t* __restrict__ Tbf) {
    __shared__ __align__(16) ushort_t Ls[128 * 72];   // [b 128][j 64] swizzled
    int wg = blockIdx.x;
    int j0 = (wg & 511) * 64;
    int bt = wg >> 9;                   // 0..1
    int tid = threadIdx.x;
    int wave = tid >> 6, lane = tid & 63;
    int rowi = lane & 15, q = lane >> 4;
    int b0w = bt * 128 + wave * 32;

    f32x4 acc[4][2];
    const f32x4 zero = {0.f, 0.f, 0.f, 0.f};
    for (int ta = 0; ta < 4; ++ta)
        for (int tb = 0; tb < 2; ++tb) acc[ta][tb] = zero;

    for (int ks = 0; ks < 2; ++ks) {
        bf16x8 a[4], bb[2];
        for (int ta = 0; ta < 4; ++ta)
            a[ta] = *(const bf16x8*)(psiT + (size_t)(j0 + ta * 16 + rowi) * 64 +
                                     ks * 32 + q * 8);
        for (int tb = 0; tb < 2; ++tb)
            bb[tb] = *(const bf16x8*)(ybf + (size_t)(b0w + tb * 16 + rowi) * 64 +
                                      ks * 32 + q * 8);
        for (int ta = 0; ta < 4; ++ta)
            for (int tb = 0; tb < 2; ++tb)
                acc[ta][tb] = __builtin_amdgcn_mfma_f32_16x16x32_bf16(
                    a[ta], bb[tb], acc[ta][tb], 0, 0, 0);
    }
    for (int ta = 0; ta < 4; ++ta)
        for (int tb = 0; tb < 2; ++tb) {
            int bl = wave * 32 + tb * 16 + rowi;      // local b in [0,128)
            int jl = ta * 16 + q * 4;
            uint_t lo = (uint_t)f2b(acc[ta][tb][0]) | ((uint_t)f2b(acc[ta][tb][1]) << 16);
            uint_t hi = (uint_t)f2b(acc[ta][tb][2]) | ((uint_t)f2b(acc[ta][tb][3]) << 16);
            int idx = bl * 72 + ((((jl >> 3) + 2 * bl) & 7) << 3) + (jl & 7);
            *(uint2*)&Ls[idx] = make_uint2(lo, hi);
        }
    __syncthreads();
    for (int pass = 0; pass < 4; ++pass) {
        int b = pass * 32 + (tid >> 3);               // local b
        int ch = tid & 7;
        uint4 v = *(const uint4*)&Ls[b * 72 + ch * 8];
        int x = (ch - 2 * b) & 7;
        *(uint4*)(Tbf + (size_t)(bt * 128 + b) * 32768 + j0 + x * 8) = v;
    }
}

// --- Krylov: per (b,k); T in registers; grad mode writes O over T. ---------
template <int NT>
__global__ __launch_bounds__(256) void krylov_k(ushort_t* __restrict__ Tbf,
                                                const float* __restrict__ z0,
                                                const float* __restrict__ z1,
                                                float* __restrict__ out) {
    __shared__ float V[NT][64];
    __shared__ float U[NT][64];
    __shared__ float zz[64];
    int bid = blockIdx.x;
    int b = bid >> 3, k = bid & 7;
    int tid = threadIdx.x;
    int row = tid >> 2, p = tid & 3, c0 = p * 16;
    bool grad = (out == nullptr);

    const ushort_t* tbase = Tbf + (size_t)bid * 4096;
    float rowT[16];
    {
        uint4 ra = *(const uint4*)(tbase + row * 64 + c0);
        uint4 rb = *(const uint4*)(tbase + row * 64 + c0 + 8);
        uint_t wv[8] = {ra.x, ra.y, ra.z, ra.w, rb.x, rb.y, rb.z, rb.w};
        for (int i = 0; i < 8; ++i) {
            rowT[2 * i]     = __uint_as_float(wv[i] << 16);
            rowT[2 * i + 1] = __uint_as_float(wv[i] & 0xFFFF0000u);
        }
    }
    float colT[16];
    if (grad) {
#pragma unroll
        for (int i = 0; i < 16; ++i) colT[i] = b2f(tbase[(c0 + i) * 64 + row]);
    }
    if (tid < 64) {
        V[0][tid] = z0[(size_t)b * 512 + k * 64 + tid];
        zz[tid]   = z1[(size_t)b * 512 + k * 64 + tid];
    }
    __syncthreads();

    for (int l = 1; l < NT; ++l) {
        const f32x4* vp = (const f32x4*)&V[l - 1][c0];
        f32x4 v0 = vp[0], v1 = vp[1], v2 = vp[2], v3 = vp[3];
        float s0 = 0.f, s1 = 0.f, s2 = 0.f, s3 = 0.f;
#pragma unroll
        for (int i = 0; i < 4; ++i) {
            s0 = fmaf(rowT[i], v0[i], s0);
            s1 = fmaf(rowT[4 + i], v1[i], s1);
            s2 = fmaf(rowT[8 + i], v2[i], s2);
            s3 = fmaf(rowT[12 + i], v3[i], s3);
        }
        float s = qsum4((s0 + s1) + (s2 + s3));
        if (p == 0) V[l][row] = s;
        __syncthreads();
    }

    if (!grad) {
        if (tid < 64) {
            float zh = 0.f;
#pragma unroll
            for (int l = 0; l < NT; ++l) zh = fmaf(INVF[l], V[l][tid], zh);
            out[(size_t)b * 512 + k * 64 + tid] = zh;
        }
        return;
    }

    if (tid < 64) {
        float zh = 0.f;
#pragma unroll
        for (int l = 0; l < NT; ++l) zh = fmaf(INVF[l], V[l][tid], zh);
        U[0][tid] = zh - zz[tid];
    }
    __syncthreads();

    for (int j = 1; j < NT; ++j) {
        const f32x4* up = (const f32x4*)&U[j - 1][c0];
        f32x4 u0 = up[0], u1 = up[1], u2 = up[2], u3 = up[3];
        float s0 = 0.f, s1 = 0.f, s2 = 0.f, s3 = 0.f;
#pragma unroll
        for (int i = 0; i < 4; ++i) {
            s0 = fmaf(colT[i], u0[i], s0);
            s1 = fmaf(colT[4 + i], u1[i], s1);
            s2 = fmaf(colT[8 + i], u2[i], s2);
            s3 = fmaf(colT[12 + i], u3[i], s3);
        }
        float s = qsum4((s0 + s1) + (s2 + s3));
        if (p == 0) U[j][row] = s;
        __syncthreads();
    }

    float W[NT];
#pragma unroll
    for (int l = 0; l < NT; ++l) {
        float w = 0.f;
#pragma unroll
        for (int j = 0; j < NT; ++j) w = fmaf(INVF[j + l + 1], U[j][row], w);
        W[l] = w;
    }
    float o[16];
#pragma unroll
    for (int i = 0; i < 16; ++i) o[i] = 0.f;
#pragma unroll
    for (int l = 0; l < NT; ++l) {
        const f32x4* vp = (const f32x4*)&V[l][c0];
        f32x4 a0 = vp[0], a1 = vp[1], a2 = vp[2], a3 = vp[3];
        float w = W[l];
#pragma unroll
        for (int i = 0; i < 4; ++i) {
            o[i]      = fmaf(w, a0[i], o[i]);
            o[4 + i]  = fmaf(w, a1[i], o[4 + i]);
            o[8 + i]  = fmaf(w, a2[i], o[8 + i]);
            o[12 + i] = fmaf(w, a3[i], o[12 + i]);
        }
    }
    uint_t ow[8];
#pragma unroll
    for (int i = 0; i < 8; ++i)
        ow[i] = (uint_t)f2b(o[2 * i]) | ((uint_t)f2b(o[2 * i + 1]) << 16);
    uint4* op = (uint4*)(Tbf + (size_t)bid * 4096 + row * 64 + c0);
    op[0] = make_uint4(ow[0], ow[1], ow[2], ow[3]);
    op[1] = make_uint4(ow[4], ow[5], ow[6], ow[7]);
}

// --- GEMM2: gpart[kc][b][m] = sum_{uv in chunk} O[b][.] psiB[m][.] ---------
// grid 256 = 4 bt x 64 kc (champion tiling/traffic); block 512 = 8 waves,
// each wave takes a 64-uv slice (2 ks) -> 8 waves/CU latency hiding (was 4).
// 8 private LDS partials (139.3 KB, 1 wg/CU), ONE barrier, pairwise reduce.
__global__ __launch_bounds__(512) void gemm2_k(const ushort_t* __restrict__ Obf,
                                               const ushort_t* __restrict__ psiB,
                                               float* __restrict__ gpart) {
    __shared__ __align__(16) float Lg[8][64 * 68];    // [w][b 64][m 64] str 68
    int bt = blockIdx.x & 3;
    int kc = blockIdx.x >> 2;          // 0..63
    int k = kc >> 3;
    int uv0 = (kc & 7) * 512;
    int tid = threadIdx.x, wave = tid >> 6, lane = tid & 63;
    int rowi = lane & 15, q = lane >> 4;

    f32x4 acc[4][4];
    const f32x4 zero = {0.f, 0.f, 0.f, 0.f};
    for (int ta = 0; ta < 4; ++ta)
        for (int tb = 0; tb < 4; ++tb) acc[ta][tb] = zero;

    for (int ks = 0; ks < 2; ++ks) {
        int off = uv0 + wave * 64 + ks * 32 + q * 8;
        bf16x8 a[4], bb[4];
        for (int ta = 0; ta < 4; ++ta)
            a[ta] = *(const bf16x8*)(psiB + (size_t)k * 262144 +
                                     (size_t)(ta * 16 + rowi) * 4096 + off);
        for (int tb = 0; tb < 4; ++tb)
            bb[tb] = *(const bf16x8*)(Obf +
                                      (size_t)(bt * 64 + tb * 16 + rowi) * 32768 +
                                      k * 4096 + off);
        for (int ta = 0; ta < 4; ++ta)
            for (int tb = 0; tb < 4; ++tb)
                acc[ta][tb] = __builtin_amdgcn_mfma_f32_16x16x32_bf16(
                    a[ta], bb[tb], acc[ta][tb], 0, 0, 0);
    }
    float* lw = &Lg[wave][0];
    for (int ta = 0; ta < 4; ++ta)
        for (int tb = 0; tb < 4; ++tb)
            *(f32x4*)&lw[(tb * 16 + rowi) * 68 + ta * 16 + q * 4] = acc[ta][tb];
    __syncthreads();

    int b = tid >> 3, m0 = (tid & 7) * 8;            // 64 b x 8 m per thread
    const float* l0 = &Lg[0][b * 68 + m0];
    float* gp = gpart + (size_t)kc * 16384 + (size_t)(bt * 64 + b) * 64 + m0;
#pragma unroll
    for (int i = 0; i < 2; ++i) {
        f32x4 s0 = *(const f32x4*)(l0 + 0 * 4352 + 4 * i);
        f32x4 s1 = *(const f32x4*)(l0 + 1 * 4352 + 4 * i);
        f32x4 s2 = *(const f32x4*)(l0 + 2 * 4352 + 4 * i);
        f32x4 s3 = *(const f32x4*)(l0 + 3 * 4352 + 4 * i);
        f32x4 s4 = *(const f32x4*)(l0 + 4 * 4352 + 4 * i);
        f32x4 s5 = *(const f32x4*)(l0 + 5 * 4352 + 4 * i);
        f32x4 s6 = *(const f32x4*)(l0 + 6 * 4352 + 4 * i);
        f32x4 s7 = *(const f32x4*)(l0 + 7 * 4352 + 4 * i);
        f32x4 s = ((s0 + s1) + (s2 + s3)) + ((s4 + s5) + (s6 + s7));
        *(f32x4*)(gp + 4 * i) = s;
    }
}

// --- FISTA: reduce 64 partials + prox; 256 wgs x 256 thr (full CU coverage).
// Thread (pg,e) sums partials [pg*16, pg*16+16) for element idx (4 chains of
// 4); LDS 4-way reduce; 64 threads do prox + state writes.  Identical gpart
// traffic to the 64-wg champion, 4x CU coverage, 4x shorter load chains.
__global__ __launch_bounds__(256) void fista_update(const float* __restrict__ gpart,
                                                    float* __restrict__ cb,
                                                    float* __restrict__ yb,
                                                    ushort_t* __restrict__ cbf,
                                                    ushort_t* __restrict__ ybf,
                                                    int iter) {
    __shared__ float red[4][64];
    int e = threadIdx.x & 63, pg = threadIdx.x >> 6;
    int idx = blockIdx.x * 64 + e;
    int p0 = pg * 16;
    float a0 = 0.f, a1 = 0.f, a2 = 0.f, a3 = 0.f;
#pragma unroll
    for (int i = 0; i < 16; i += 4) {
        a0 += gpart[(size_t)(p0 + i) * 16384 + idx];
        a1 += gpart[(size_t)(p0 + i + 1) * 16384 + idx];
        a2 += gpart[(size_t)(p0 + i + 2) * 16384 + idx];
        a3 += gpart[(size_t)(p0 + i + 3) * 16384 + idx];
    }
    red[pg][e] = (a0 + a1) + (a2 + a3);
    __syncthreads();
    if (pg == 0) {
        float gv = (red[0][e] + red[1][e]) + (red[2][e] + red[3][e]);
        float t = 1.f;
        for (int s = 0; s < iter; ++s) t = 0.5f * (1.f + sqrtf(1.f + 4.f * t * t));
        float tn = 0.5f * (1.f + sqrtf(1.f + 4.f * t * t));
        float beta = (t - 1.f) / tn;
        float co = cb[idx], yo = yb[idx];
        float a = yo - 0.01f * gv;
        float thr = 0.01f * 0.05f;
        float cn = copysignf(fmaxf(fabsf(a) - thr, 0.f), a);
        float yn = cn + beta * (cn - co);
        cb[idx] = cn;
        yb[idx] = yn;
        cbf[idx] = f2b(cn);
        ybf[idx] = f2b(yn);
    }
}

extern "C" void kernel_launch(void* const* d_in, const int* in_sizes, int n_in,
                              void* d_out, int out_size, void* d_ws, size_t ws_size,
                              hipStream_t stream) {
    const float* z0 = (const float*)d_in[0];
    const float* z1 = (const float*)d_in[1];
    const float* psi = (const float*)d_in[2];
    float* out = (float*)d_out;

    char* w = (char*)d_ws;
    ushort_t* TO    = (ushort_t*)(w);                 // 16,777,216  (T, then O)
    ushort_t* psiB  = (ushort_t*)(w + 16777216);      //  4,194,304
    ushort_t* psiT  = (ushort_t*)(w + 20971520);      //  4,194,304
    float*    gpart = (float*)(w + 25165824);         //  4,194,304  (64 partials)
    float*    cbuf  = (float*)(w + 29360128);         //     65,536
    float*    ybuf  = (float*)(w + 29425664);         //     65,536
    ushort_t* cbf   = (ushort_t*)(w + 29491200);      //     32,768
    ushort_t* ybf   = (ushort_t*)(w + 29523968);      //     32,768
    // total 29,556,736 B

    // fused prologue: iter-0 outer product (2048 wgs) + psi conversion with
    // tile-transposed psiT + c/y zeroing (512 wgs).  One dispatch.
    prep0_k<<<2560, 256, 0, stream>>>(psi, psiB, psiT,
                                      (uint4*)(w + 29360128), z0, z1, TO);

    // iter 0 tail
    gemm2_k<<<256, 512, 0, stream>>>(TO, psiB, gpart);
    fista_update<<<256, 256, 0, stream>>>(gpart, cbuf, ybuf, cbf, ybf, 0);

    for (int it = 1; it < 20; ++it) {
        gemm1_k<<<1024, 256, 0, stream>>>(ybf, psiT, TO);
        krylov_k<3><<<2048, 256, 0, stream>>>(TO, z0, z1, nullptr);
        gemm2_k<<<256, 512, 0, stream>>>(TO, psiB, gpart);
        fista_update<<<256, 256, 0, stream>>>(gpart, cbuf, ybuf, cbf, ybf, it);
    }

    gemm1_k<<<1024, 256, 0, stream>>>(cbf, psiT, TO);
    krylov_k<6><<<2048, 256, 0, stream>>>(TO, z0, z1, out);
}